// Round 12
// baseline (1682.692 us; speedup 1.0000x reference)
//
#include <hip/hip_runtime.h>
#include <hip/hip_bf16.h>
#include <math.h>

constexpr int NP  = 32768;  // mesh points
constexpr int HH  = 8;      // heads

typedef short bf16x8 __attribute__((ext_vector_type(8)));
typedef float f32x4  __attribute__((ext_vector_type(4)));

__device__ __forceinline__ float gelu_f(float x) {
    return 0.5f * x * (1.0f + erff(x * 0.70710678118654752f));
}

__device__ __forceinline__ unsigned short f2bf(float x) {
    union { float f; unsigned u; } v; v.f = x;
    unsigned r = v.u + 0x7fffu + ((v.u >> 16) & 1u);
    return (unsigned short)(r >> 16);
}

// ---------------------------------------------------------------------------
// Weight prep: src [G][K][256] fp32 -> dst [G][256][K] bf16 (transposed)
// ---------------------------------------------------------------------------
__global__ __launch_bounds__(256) void transpose_bf16_k(
    const float* __restrict__ src, unsigned short* __restrict__ dst, int K)
{
    __shared__ float tile[32][33];
    int g = blockIdx.z;
    int k0 = blockIdx.x * 32, c0 = blockIdx.y * 32;
    int tx = threadIdx.x & 31, ty = threadIdx.x >> 5;
    const float* s = src + (size_t)g * K * 256;
    unsigned short* d = dst + (size_t)g * 256 * K;
    #pragma unroll
    for (int rr = 0; rr < 4; ++rr) {
        int r = ty + rr * 8;
        tile[r][tx] = s[(size_t)(k0 + r) * 256 + c0 + tx];
    }
    __syncthreads();
    #pragma unroll
    for (int rr = 0; rr < 4; ++rr) {
        int r = ty + rr * 8;
        d[(size_t)(c0 + r) * K + k0 + tx] = f2bf(tile[tx][r]);
    }
}

// Same, but scales row k by g[z*256+k] before rounding (LN-fold weights g.W)
__global__ __launch_bounds__(256) void transpose_scale_bf16_k(
    const float* __restrict__ src, const float* __restrict__ g,
    unsigned short* __restrict__ dst, int K)
{
    __shared__ float tile[32][33];
    int z = blockIdx.z;
    int k0 = blockIdx.x * 32, c0 = blockIdx.y * 32;
    int tx = threadIdx.x & 31, ty = threadIdx.x >> 5;
    const float* s = src + (size_t)z * K * 256;
    unsigned short* d = dst + (size_t)z * 256 * K;
    #pragma unroll
    for (int rr = 0; rr < 4; ++rr) {
        int r = ty + rr * 8;
        tile[r][tx] = s[(size_t)(k0 + r) * 256 + c0 + tx];
    }
    __syncthreads();
    float gs = g[z * 256 + k0 + tx];
    #pragma unroll
    for (int rr = 0; rr < 4; ++rr) {
        int r = ty + rr * 8;
        d[(size_t)(c0 + r) * K + k0 + tx] = f2bf(gs * tile[tx][r]);
    }
}

// c2[z][c] = sum_k g[z][k] W[z][k][c] ; c1[z][c] = sum_k b[z][k] W[z][k][c]
__global__ __launch_bounds__(256) void colsum_k(
    const float* __restrict__ W, const float* __restrict__ g,
    const float* __restrict__ b, float* __restrict__ c2, float* __restrict__ c1)
{
    int z = blockIdx.z, c = threadIdx.x;
    const float* Wz = W + (size_t)z * 65536;
    const float* gz = g + z * 256;
    const float* bz = b + z * 256;
    float s2 = 0.f, s1 = 0.f;
    for (int k = 0; k < 256; ++k) {
        float w = Wz[k * 256 + c];
        s2 += gz[k] * w;
        s1 += bz[k] * w;
    }
    c2[z * 256 + c] = s2;
    c1[z * 256 + c] = s1;
}

// ---------------------------------------------------------------------------
// MFMA GEMM (R12): BK=128. At K=256 the BK=64 version ran 4 K-iterations x
// 2 barriers with only 32 MFMA/wave between them — barrier-drain dominated.
// BK=128 halves barriers, doubles MFMA per barrier. LDS 64 KB -> 2 blocks/CU.
// ---------------------------------------------------------------------------
template<bool GENA, bool AF32, bool LNFOLD, bool DOGELU, bool RESID, bool STATS, bool PERM>
__global__ __launch_bounds__(256) void gemm_bf(
    const unsigned short* __restrict__ Ah, const float* __restrict__ Af,
    const unsigned short* __restrict__ Wt,
    const float* __restrict__ bias, const float* __restrict__ bias2,
    float* __restrict__ outF, unsigned short* __restrict__ outH,
    const float* __restrict__ stats_in, float* __restrict__ stats_out,
    const float* __restrict__ c1v, const float* __restrict__ c2vec,
    const float* __restrict__ genx, const float* __restrict__ genw1,
    const float* __restrict__ genb1, int K)
{
    __shared__ __align__(16) unsigned short As[128 * 128];
    __shared__ __align__(16) unsigned short Bs[128 * 128];
    __shared__ float rmean[LNFOLD ? 128 : 1];
    __shared__ float rrstd[LNFOLD ? 128 : 1];
    __shared__ float w1s[GENA ? 1536 : 1];
    __shared__ float b1s[GENA ? 512 : 1];
    __shared__ float x3s[GENA ? 512 : 1];

    const int tid = threadIdx.x;
    const int rBase = blockIdx.x * 128, cBase = blockIdx.y * 128;

    if constexpr (GENA) {
        for (int i2 = tid; i2 < 1536; i2 += 256) w1s[i2] = genw1[i2];
        for (int i2 = tid; i2 < 512; i2 += 256) b1s[i2] = genb1[i2];
        if (tid < 128) {
            x3s[tid * 4 + 0] = genx[(size_t)(rBase + tid) * 3 + 0];
            x3s[tid * 4 + 1] = genx[(size_t)(rBase + tid) * 3 + 1];
            x3s[tid * 4 + 2] = genx[(size_t)(rBase + tid) * 3 + 2];
        }
        __syncthreads();
    }
    if constexpr (LNFOLD) {
        if (tid < 128) {
            const float* sp = stats_in + (size_t)(rBase + tid) * 8;
            float4 s0 = *(const float4*)sp;
            float4 s1 = *(const float4*)(sp + 4);
            float mean = (s0.x + s0.z + s1.x + s1.z) * (1.f / 256.f);
            float ex2  = (s0.y + s0.w + s1.y + s1.w) * (1.f / 256.f);
            rmean[tid] = mean;
            rrstd[tid] = rsqrtf(fmaxf(ex2 - mean * mean, 0.f) + 1e-5f);
        }
        __syncthreads();
    }

    f32x4 acc[4][4];
    #pragma unroll
    for (int i = 0; i < 4; ++i)
        #pragma unroll
        for (int j = 0; j < 4; ++j)
            acc[i][j] = (f32x4){0.f, 0.f, 0.f, 0.f};

    const int lane = tid & 63, wid = tid >> 6;
    const int wr = wid >> 1, wc = wid & 1;
    const int lrow = lane & 15, quad = lane >> 4;
    const int srow = tid >> 4;   // 0..15
    const int sch  = tid & 15;   // k-chunk of 8 (16 per 128-k row)

    for (int kc = 0; kc < K; kc += 128) {
        if constexpr (GENA) {
            #pragma unroll
            for (int it = 0; it < 8; ++it) {
                int row = srow + it * 16;
                float x0 = x3s[row * 4 + 0], x1 = x3s[row * 4 + 1], x2 = x3s[row * 4 + 2];
                unsigned short pk[8];
                #pragma unroll
                for (int j = 0; j < 8; ++j) {
                    int k = kc + sch * 8 + j;
                    float t = x0 * w1s[k] + x1 * w1s[512 + k] + x2 * w1s[1024 + k] + b1s[k];
                    pk[j] = f2bf(gelu_f(t));
                }
                *(uint4*)&As[row * 128 + ((sch ^ (row & 7)) << 3)] = *(uint4*)pk;
            }
        } else if constexpr (AF32) {
            #pragma unroll
            for (int it = 0; it < 8; ++it) {
                int row = srow + it * 16;
                const float* ap = Af + (size_t)(rBase + row) * K + kc + sch * 8;
                float4 a0 = *(const float4*)ap;
                float4 a1 = *(const float4*)(ap + 4);
                unsigned short pk[8];
                pk[0] = f2bf(a0.x); pk[1] = f2bf(a0.y); pk[2] = f2bf(a0.z); pk[3] = f2bf(a0.w);
                pk[4] = f2bf(a1.x); pk[5] = f2bf(a1.y); pk[6] = f2bf(a1.z); pk[7] = f2bf(a1.w);
                *(uint4*)&As[row * 128 + ((sch ^ (row & 7)) << 3)] = *(uint4*)pk;
            }
        } else {
            #pragma unroll
            for (int it = 0; it < 8; ++it) {
                int row = srow + it * 16;
                uint4 av = *(const uint4*)(Ah + (size_t)(rBase + row) * K + kc + sch * 8);
                *(uint4*)&As[row * 128 + ((sch ^ (row & 7)) << 3)] = av;
            }
        }
        #pragma unroll
        for (int it = 0; it < 8; ++it) {
            int n = srow + it * 16;
            uint4 wv_ = *(const uint4*)(Wt + (size_t)(cBase + n) * K + kc + sch * 8);
            *(uint4*)&Bs[n * 128 + ((sch ^ (n & 7)) << 3)] = wv_;
        }
        __syncthreads();
        #pragma unroll
        for (int ks = 0; ks < 4; ++ks) {
            bf16x8 af[4], bfr[4];
            #pragma unroll
            for (int t = 0; t < 4; ++t) {
                int row = wr * 64 + t * 16 + lrow;
                af[t] = *(bf16x8*)&As[row * 128 + (((ks * 4 + quad) ^ (row & 7)) << 3)];
                int n = wc * 64 + t * 16 + lrow;
                bfr[t] = *(bf16x8*)&Bs[n * 128 + (((ks * 4 + quad) ^ (n & 7)) << 3)];
            }
            #pragma unroll
            for (int ti = 0; ti < 4; ++ti)
                #pragma unroll
                for (int tj = 0; tj < 4; ++tj)
                    acc[ti][tj] = __builtin_amdgcn_mfma_f32_16x16x32_bf16(
                        af[ti], bfr[tj], acc[ti][tj], 0, 0, 0);
        }
        __syncthreads();
    }

    float c1b[4], c2r[4];
    #pragma unroll
    for (int tj = 0; tj < 4; ++tj) {
        int gcol = cBase + wc * 64 + tj * 16 + lrow;
        float b = bias[gcol];
        if (bias2) b += bias2[gcol];
        if constexpr (LNFOLD) {
            c1b[tj] = c1v[gcol] + b;
            c2r[tj] = c2vec[gcol];
        } else {
            c1b[tj] = b;
            c2r[tj] = 0.f;
        }
    }
    #pragma unroll
    for (int ti = 0; ti < 4; ++ti) {
        #pragma unroll
        for (int r = 0; r < 4; ++r) {
            int rib = wr * 64 + ti * 16 + quad * 4 + r;
            int grow = rBase + rib;
            float mean = 0.f, rstd = 1.f;
            if constexpr (LNFOLD) { mean = rmean[rib]; rstd = rrstd[rib]; }
            float vv[4];
            #pragma unroll
            for (int tj = 0; tj < 4; ++tj) {
                float t = acc[ti][tj][r];
                float v;
                if constexpr (LNFOLD) v = rstd * (t - mean * c2r[tj]) + c1b[tj];
                else                  v = t + c1b[tj];
                if constexpr (DOGELU) v = gelu_f(v);
                vv[tj] = v;
            }
            if constexpr (RESID) {
                #pragma unroll
                for (int tj = 0; tj < 4; ++tj) {
                    int gcol = cBase + wc * 64 + tj * 16 + lrow;
                    vv[tj] += outF[(size_t)grow * 256 + gcol];
                }
            }
            if constexpr (STATS) {
                float rs = vv[0] + vv[1] + vv[2] + vv[3];
                float rq = vv[0]*vv[0] + vv[1]*vv[1] + vv[2]*vv[2] + vv[3]*vv[3];
                #pragma unroll
                for (int m = 1; m < 16; m <<= 1) {
                    rs += __shfl_xor(rs, m);
                    rq += __shfl_xor(rq, m);
                }
                if (lrow == 0) {
                    stats_out[(size_t)grow * 8 + (blockIdx.y * 2 + wc) * 2 + 0] = rs;
                    stats_out[(size_t)grow * 8 + (blockIdx.y * 2 + wc) * 2 + 1] = rq;
                }
            }
            #pragma unroll
            for (int tj = 0; tj < 4; ++tj) {
                int gcol = cBase + wc * 64 + tj * 16 + lrow;
                if constexpr (PERM) {
                    outF[(size_t)(gcol >> 5) * NP * 32 + (size_t)grow * 32 + (gcol & 31)] = vv[tj];
                } else {
                    if (outF) outF[(size_t)grow * 256 + gcol] = vv[tj];
                    if (outH) outH[(size_t)grow * 256 + gcol] = f2bf(vv[tj]);
                }
            }
        }
    }
}

// ---------------------------------------------------------------------------
// kv5 (unchanged, working): wk in registers, deterministic partials.
// ---------------------------------------------------------------------------
__global__ __launch_bounds__(512) void kv5_kernel(
    const float* __restrict__ xm2, const float* __restrict__ wk,
    const float* __restrict__ wv, const float* __restrict__ tk_arr,
    float* __restrict__ partials, int layer)
{
    __shared__ __align__(16) float smem[5120];
    float* xs  = smem;
    float* vs  = smem + 2048;
    float* wvs = smem + 4096;
    float* red = smem;

    const int tid = threadIdx.x;
    const int h = blockIdx.y;
    const int rowBase = blockIdx.x * 512;
    const int p  = tid >> 6;
    const int dg = tid & 63;

    float tk = fminf(fmaxf(tk_arr[layer * 8 + h], 0.1f), 2.0f);
    float invtk = 1.0f / tk;
    for (int i = tid; i < 1024; i += 512) wvs[i] = wv[i];

    float wkr0[32], wkr1[32];
    #pragma unroll
    for (int j = 0; j < 32; ++j) {
        float2 w2 = *(const float2*)(wk + j * 128 + dg * 2);
        wkr0[j] = w2.x; wkr1[j] = w2.y;
    }

    float acc0[32], acc1[32];
    #pragma unroll
    for (int c = 0; c < 32; ++c) { acc0[c] = 0.f; acc1[c] = 0.f; }
    float se0 = 0.f, se1 = 0.f;

    const float* src = xm2 + (size_t)h * NP * 32 + (size_t)rowBase * 32;
    const int lr = tid >> 3, lc = (tid & 7) * 4;

    for (int tile = 0; tile < 8; ++tile) {
        __syncthreads();
        *(float4*)&xs[lr * 32 + lc] =
            *(const float4*)(src + (size_t)(tile * 64 + lr) * 32 + lc);
        __syncthreads();
        {
            float a0 = 0.f, a1 = 0.f, a2 = 0.f, a3 = 0.f;
            #pragma unroll
            for (int j = 0; j < 32; ++j) {
                float xv = xs[lr * 32 + j];
                float4 w4 = *(const float4*)&wvs[j * 32 + lc];
                a0 += xv * w4.x; a1 += xv * w4.y; a2 += xv * w4.z; a3 += xv * w4.w;
            }
            float4 o; o.x = a0; o.y = a1; o.z = a2; o.w = a3;
            *(float4*)&vs[lr * 32 + lc] = o;
        }
        __syncthreads();
        #pragma unroll 1
        for (int t = 0; t < 8; ++t) {
            int n = p * 8 + t;
            float l0 = 0.f, l1 = 0.f;
            #pragma unroll
            for (int j4 = 0; j4 < 8; ++j4) {
                float4 x4 = *(const float4*)&xs[n * 32 + j4 * 4];
                l0 += x4.x * wkr0[j4 * 4 + 0] + x4.y * wkr0[j4 * 4 + 1]
                    + x4.z * wkr0[j4 * 4 + 2] + x4.w * wkr0[j4 * 4 + 3];
                l1 += x4.x * wkr1[j4 * 4 + 0] + x4.y * wkr1[j4 * 4 + 1]
                    + x4.z * wkr1[j4 * 4 + 2] + x4.w * wkr1[j4 * 4 + 3];
            }
            float e0 = __expf(fminf(fmaxf(l0 * invtk, -60.f), 60.f));
            float e1 = __expf(fminf(fmaxf(l1 * invtk, -60.f), 60.f));
            se0 += e0; se1 += e1;
            #pragma unroll
            for (int cc = 0; cc < 8; ++cc) {
                float4 v4 = *(const float4*)&vs[n * 32 + cc * 4];
                acc0[cc*4+0] += e0 * v4.x; acc0[cc*4+1] += e0 * v4.y;
                acc0[cc*4+2] += e0 * v4.z; acc0[cc*4+3] += e0 * v4.w;
                acc1[cc*4+0] += e1 * v4.x; acc1[cc*4+1] += e1 * v4.y;
                acc1[cc*4+2] += e1 * v4.z; acc1[cc*4+3] += e1 * v4.w;
            }
        }
    }

    float* outp = partials + ((size_t)h * 64 + blockIdx.x) * 4224;
    #pragma unroll
    for (int cc = 0; cc < 8; ++cc) {
        __syncthreads();
        #pragma unroll
        for (int ci = 0; ci < 4; ++ci) {
            red[tid * 9 + ci]     = acc0[cc * 4 + ci];
            red[tid * 9 + 4 + ci] = acc1[cc * 4 + ci];
        }
        __syncthreads();
        int d = tid >> 2, ci = tid & 3;
        float s = 0.f;
        #pragma unroll
        for (int pp = 0; pp < 8; ++pp)
            s += red[(pp * 64 + (d >> 1)) * 9 + (d & 1) * 4 + ci];
        outp[d * 32 + cc * 4 + ci] = s;
    }
    __syncthreads();
    red[tid * 9 + 0] = se0;
    red[tid * 9 + 1] = se1;
    __syncthreads();
    if (tid < 128) {
        int d = tid;
        float s = 0.f;
        #pragma unroll
        for (int pp = 0; pp < 8; ++pp)
            s += red[(pp * 64 + (d >> 1)) * 9 + (d & 1)];
        outp[4096 + d] = s;
    }
}

__global__ __launch_bounds__(256) void kv_reduce_kernel(
    const float* __restrict__ partials, float* __restrict__ kvU,
    float* __restrict__ sumexp)
{
    int gid = blockIdx.x * 256 + threadIdx.x;
    if (gid >= 8 * 4224) return;
    int h = gid / 4224, idx = gid % 4224;
    const float* base = partials + (size_t)h * 64 * 4224 + idx;
    float s = 0.f;
    #pragma unroll 8
    for (int c = 0; c < 64; ++c) s += base[(size_t)c * 4224];
    if (idx < 4096) kvU[(size_t)h * 4096 + idx] = s;
    else sumexp[h * 128 + (idx - 4096)] = s;
}

// ---------------------------------------------------------------------------
// qkv3 (unchanged R9-proven fp32 version).
// ---------------------------------------------------------------------------
__global__ __launch_bounds__(256) void qkv3_kernel(
    const float* __restrict__ xm2, const float* __restrict__ wq,
    const float* __restrict__ tq_arr,
    const float* __restrict__ kvU, const float* __restrict__ sumexp,
    float* __restrict__ outD, int layer)
{
    __shared__ __align__(16) float xsw[4096];
    __shared__ __align__(16) float wqs[4096];
    __shared__ __align__(16) float kvs[4096];
    __shared__ float ises[128];

    const int tid = threadIdx.x;
    const int h = blockIdx.y;
    const int rowBase = blockIdx.x * 128;
    const int rt = tid >> 4;
    const int dt = tid & 15;

    float tq = fminf(fmaxf(tq_arr[layer * 8 + h], 0.1f), 2.0f);
    float invtq = 1.0f / tq;

    if (tid < 128) ises[tid] = 1.0f / sumexp[h * 128 + tid];
    #pragma unroll
    for (int it = 0; it < 4; ++it) {
        int i4 = tid + it * 256;
        int k = i4 >> 5, c4 = i4 & 31;
        float4 v = *(const float4*)(wq + (size_t)k * 128 + c4 * 4);
        int c4s = c4 ^ ((c4 >> 1) & 7);
        *(float4*)&wqs[k * 128 + c4s * 4] = v;
    }
    {
        const float* kvsrc = kvU + (size_t)h * 4096;
        #pragma unroll
        for (int it = 0; it < 4; ++it) {
            int i4 = tid + it * 256;
            int d = i4 >> 3, c4 = i4 & 7;
            float4 v = *(const float4*)(kvsrc + (size_t)d * 32 + c4 * 4);
            int c4s = c4 ^ ((d >> 3) & 7);
            *(float4*)&kvs[d * 32 + c4s * 4] = v;
        }
    }
    {
        const float* src = xm2 + (size_t)h * NP * 32 + (size_t)rowBase * 32;
        #pragma unroll
        for (int it = 0; it < 4; ++it) {
            int s = tid + it * 256;
            int r = s >> 3, j4 = s & 7;
            float4 v = *(const float4*)(src + (size_t)r * 32 + j4 * 4);
            *(float4*)&xsw[r * 32 + ((j4 ^ ((r >> 3) & 7)) << 2)] = v;
        }
    }
    __syncthreads();

    const int swr = rt & 7;
    const int swd = dt & 7;

    float l[8][8];
    #pragma unroll
    for (int i = 0; i < 8; ++i)
        #pragma unroll
        for (int jd = 0; jd < 8; ++jd) l[i][jd] = 0.f;

    const int cA = (dt * 2)     ^ swd;
    const int cB = (dt * 2 + 1) ^ swd;
    #pragma unroll
    for (int j4 = 0; j4 < 8; ++j4) {
        float4 xv[8];
        #pragma unroll
        for (int i = 0; i < 8; ++i)
            xv[i] = *(const float4*)&xsw[(rt * 8 + i) * 32 + ((j4 ^ swr) << 2)];
        #pragma unroll
        for (int kk = 0; kk < 4; ++kk) {
            int k = j4 * 4 + kk;
            float4 wa = *(const float4*)&wqs[k * 128 + cA * 4];
            float4 wb = *(const float4*)&wqs[k * 128 + cB * 4];
            #pragma unroll
            for (int i = 0; i < 8; ++i) {
                float xx = (kk == 0) ? xv[i].x : (kk == 1) ? xv[i].y
                         : (kk == 2) ? xv[i].z : xv[i].w;
                l[i][0] += xx * wa.x; l[i][1] += xx * wa.y;
                l[i][2] += xx * wa.z; l[i][3] += xx * wa.w;
                l[i][4] += xx * wb.x; l[i][5] += xx * wb.y;
                l[i][6] += xx * wb.z; l[i][7] += xx * wb.w;
            }
        }
    }

    float isr[8];
    #pragma unroll
    for (int jd = 0; jd < 8; ++jd) isr[jd] = ises[dt * 8 + jd];
    #pragma unroll
    for (int i = 0; i < 8; ++i) {
        float m = l[i][0];
        #pragma unroll
        for (int jd = 1; jd < 8; ++jd) m = fmaxf(m, l[i][jd]);
        m = fmaxf(m, __shfl_xor(m, 1));
        m = fmaxf(m, __shfl_xor(m, 2));
        m = fmaxf(m, __shfl_xor(m, 4));
        m = fmaxf(m, __shfl_xor(m, 8));
        float s = 0.f;
        #pragma unroll
        for (int jd = 0; jd < 8; ++jd) {
            float e = __expf((l[i][jd] - m) * invtq);
            l[i][jd] = e;
            s += e;
        }
        s += __shfl_xor(s, 1);
        s += __shfl_xor(s, 2);
        s += __shfl_xor(s, 4);
        s += __shfl_xor(s, 8);
        float inv = 1.0f / s;
        #pragma unroll
        for (int jd = 0; jd < 8; ++jd) l[i][jd] *= inv * isr[jd];
    }

    const int b0 = dt & 1, b1 = (dt >> 1) & 1, b2 = (dt >> 2) & 1, b3 = (dt >> 3) & 1;
    #pragma unroll
    for (int chunk = 0; chunk < 4; ++chunk) {
        float o[8][8];
        #pragma unroll
        for (int i = 0; i < 8; ++i)
            #pragma unroll
            for (int c = 0; c < 8; ++c) o[i][c] = 0.f;
        const int kA = (chunk * 2)     ^ swd;
        const int kB = (chunk * 2 + 1) ^ swd;
        #pragma unroll
        for (int jd = 0; jd < 8; ++jd) {
            int d = dt * 8 + jd;
            float4 ka = *(const float4*)&kvs[d * 32 + kA * 4];
            float4 kb = *(const float4*)&kvs[d * 32 + kB * 4];
            #pragma unroll
            for (int i = 0; i < 8; ++i) {
                float p = l[i][jd];
                o[i][0] += p * ka.x; o[i][1] += p * ka.y;
                o[i][2] += p * ka.z; o[i][3] += p * ka.w;
                o[i][4] += p * kb.x; o[i][5] += p * kb.y;
                o[i][6] += p * kb.z; o[i][7] += p * kb.w;
            }
        }
        float t1[4][8];
        #pragma unroll
        for (int i = 0; i < 4; ++i)
            #pragma unroll
            for (int c = 0; c < 8; ++c) {
                float keep = b0 ? o[i + 4][c] : o[i][c];
                float send = b0 ? o[i][c] : o[i + 4][c];
                t1[i][c] = keep + __shfl_xor(send, 1);
            }
        float t2[2][8];
        #pragma unroll
        for (int i = 0; i < 2; ++i)
            #pragma unroll
            for (int c = 0; c < 8; ++c) {
                float keep = b1 ? t1[i + 2][c] : t1[i][c];
                float send = b1 ? t1[i][c] : t1[i + 2][c];
                t2[i][c] = keep + __shfl_xor(send, 2);
            }
        float t3[2][4];
        #pragma unroll
        for (int i = 0; i < 2; ++i)
            #pragma unroll
            for (int c = 0; c < 4; ++c) {
                float keep = b2 ? t2[i][c + 4] : t2[i][c];
                float send = b2 ? t2[i][c] : t2[i][c + 4];
                t3[i][c] = keep + __shfl_xor(send, 4);
            }
        float t4[4];
        #pragma unroll
        for (int c = 0; c < 4; ++c) {
            float keep = b3 ? t3[1][c] : t3[0][c];
            float send = b3 ? t3[0][c] : t3[1][c];
            t4[c] = keep + __shfl_xor(send, 8);
        }
        int row = rt * 8 + b0 * 4 + b1 * 2 + b3;
        float4 ov; ov.x = t4[0]; ov.y = t4[1]; ov.z = t4[2]; ov.w = t4[3];
        *(float4*)(outD + (size_t)(rowBase + row) * 256 + h * 32 + chunk * 8 + b2 * 4) = ov;
    }
}

// ---------------------------------------------------------------------------
// head: out[n] = LN(fx[n]; ln3) . head_w + head_b
// ---------------------------------------------------------------------------
__global__ __launch_bounds__(256) void head_kernel(
    const float* __restrict__ fx, const float* __restrict__ g, const float* __restrict__ b,
    const float* __restrict__ hw, const float* __restrict__ hb, float* __restrict__ out)
{
    int lane = threadIdx.x & 63;
    int row = blockIdx.x * 4 + (threadIdx.x >> 6);
    float4 v = *(const float4*)(fx + (size_t)row * 256 + lane * 4);
    float s1 = v.x + v.y + v.z + v.w;
    float s2 = v.x * v.x + v.y * v.y + v.z * v.z + v.w * v.w;
    #pragma unroll
    for (int m = 1; m < 64; m <<= 1) { s1 += __shfl_xor(s1, m); s2 += __shfl_xor(s2, m); }
    float mean = s1 * 0.00390625f;
    float rstd = rsqrtf(fmaxf(s2 * 0.00390625f - mean * mean, 0.f) + 1e-5f);
    float4 gg = *(const float4*)(g + lane * 4);
    float4 bb = *(const float4*)(b + lane * 4);
    float4 w4 = *(const float4*)(hw + lane * 4);
    float d = ((v.x - mean) * rstd * gg.x + bb.x) * w4.x
            + ((v.y - mean) * rstd * gg.y + bb.y) * w4.y
            + ((v.z - mean) * rstd * gg.z + bb.z) * w4.z
            + ((v.w - mean) * rstd * gg.w + bb.w) * w4.w;
    #pragma unroll
    for (int m = 1; m < 64; m <<= 1) d += __shfl_xor(d, m);
    if (lane == 0) out[row] = d + hb[0];
}

extern "C" void kernel_launch(void* const* d_in, const int* in_sizes, int n_in,
                              void* d_out, int out_size, void* d_ws, size_t ws_size,
                              hipStream_t stream)
{
    const float* x      = (const float*)d_in[0];
    const float* pre_w1 = (const float*)d_in[1];
    const float* pre_b1 = (const float*)d_in[2];
    const float* pre_w2 = (const float*)d_in[3];
    const float* pre_b2 = (const float*)d_in[4];
    const float* ph     = (const float*)d_in[5];
    const float* ln1_g  = (const float*)d_in[6];
    const float* ln1_b  = (const float*)d_in[7];
    const float* inp_w  = (const float*)d_in[8];
    const float* inp_b  = (const float*)d_in[9];
    const float* temp_q = (const float*)d_in[10];
    const float* temp_k = (const float*)d_in[11];
    const float* wq     = (const float*)d_in[12];
    const float* wk     = (const float*)d_in[13];
    const float* wv     = (const float*)d_in[14];
    const float* out_w1 = (const float*)d_in[15];
    const float* out_b1 = (const float*)d_in[16];
    const float* out_w2 = (const float*)d_in[17];
    const float* out_b2 = (const float*)d_in[18];
    const float* ln2_g  = (const float*)d_in[19];
    const float* ln2_b  = (const float*)d_in[20];
    const float* mlp_w1 = (const float*)d_in[21];
    const float* mlp_b1 = (const float*)d_in[22];
    const float* mlp_w2 = (const float*)d_in[23];
    const float* mlp_b2 = (const float*)d_in[24];
    const float* ln3_g  = (const float*)d_in[25];
    const float* ln3_b  = (const float*)d_in[26];
    const float* head_w = (const float*)d_in[27];
    const float* head_b = (const float*)d_in[28];
    float* out = (float*)d_out;

    float* fx = (float*)d_ws;
    float* C  = fx + (size_t)NP * 256;
    unsigned short* fxh = (unsigned short*)(C + (size_t)NP * 256);
    unsigned short* ChH = fxh + (size_t)NP * 256;
    float* scr = (float*)(ChH + (size_t)NP * 256);
    float* st = scr + (size_t)NP * 256;
    float* kv = st + (size_t)NP * 8;
    float* se = kv + 8 * 4096;
    float* c1i = se + 8 * 128;
    float* c2i = c1i + 1280;
    float* c1m = c2i + 1280;
    float* c2m = c1m + 1280;
    unsigned short* wtPre = (unsigned short*)(c2m + 1280);
    unsigned short* wtL   = wtPre + 256 * 512;

    unsigned short* wtIn = wtL;
    unsigned short* wtO1 = wtL +  5 * 65536;
    unsigned short* wtO2 = wtL + 10 * 65536;
    unsigned short* wtM1 = wtL + 15 * 65536;
    unsigned short* wtM2 = wtL + 20 * 65536;

    dim3 bt(256);

    transpose_bf16_k<<<dim3(16, 8, 1), bt, 0, stream>>>(pre_w2, wtPre, 512);
    transpose_scale_bf16_k<<<dim3(8, 8, 5), bt, 0, stream>>>(inp_w,  ln1_g, wtIn, 256);
    transpose_bf16_k<<<dim3(8, 8, 5), bt, 0, stream>>>(out_w1, wtO1, 256);
    transpose_bf16_k<<<dim3(8, 8, 5), bt, 0, stream>>>(out_w2, wtO2, 256);
    transpose_scale_bf16_k<<<dim3(8, 8, 5), bt, 0, stream>>>(mlp_w1, ln2_g, wtM1, 256);
    transpose_bf16_k<<<dim3(8, 8, 5), bt, 0, stream>>>(mlp_w2, wtM2, 256);
    colsum_k<<<dim3(1, 1, 5), bt, 0, stream>>>(inp_w,  ln1_g, ln1_b, c2i, c1i);
    colsum_k<<<dim3(1, 1, 5), bt, 0, stream>>>(mlp_w1, ln2_g, ln2_b, c2m, c1m);

    dim3 gg(256, 2);

    gemm_bf<true, false, false, false, false, true, false><<<gg, bt, 0, stream>>>(
        nullptr, nullptr, wtPre, pre_b2, ph, fx, fxh, nullptr, st,
        nullptr, nullptr, x, pre_w1, pre_b1, 512);

    for (int i = 0; i < 5; ++i) {
        gemm_bf<false, false, true, false, false, false, true><<<gg, bt, 0, stream>>>(
            fxh, nullptr, wtIn + (size_t)i * 65536, inp_b + i * 256, nullptr, C, nullptr,
            st, nullptr, c1i + i * 256, c2i + i * 256, nullptr, nullptr, nullptr, 256);
        kv5_kernel<<<dim3(64, 8), dim3(512), 0, stream>>>(
            C, wk + (size_t)i * 4096, wv + (size_t)i * 1024, temp_k, scr, i);
        kv_reduce_kernel<<<dim3(132), bt, 0, stream>>>(scr, kv, se);
        qkv3_kernel<<<dim3(256, 8), bt, 0, stream>>>(
            C, wq + (size_t)i * 4096, temp_q, kv, se, scr, i);
        gemm_bf<false, true, false, true, false, false, false><<<gg, bt, 0, stream>>>(
            nullptr, scr, wtO1 + (size_t)i * 65536, out_b1 + i * 256, nullptr,
            nullptr, ChH, nullptr, nullptr, nullptr, nullptr, nullptr, nullptr, nullptr, 256);
        gemm_bf<false, false, false, false, true, true, false><<<gg, bt, 0, stream>>>(
            ChH, nullptr, wtO2 + (size_t)i * 65536, out_b2 + i * 256, nullptr, fx, fxh,
            nullptr, st, nullptr, nullptr, nullptr, nullptr, nullptr, 256);
        gemm_bf<false, false, true, true, false, false, false><<<gg, bt, 0, stream>>>(
            fxh, nullptr, wtM1 + (size_t)i * 65536, mlp_b1 + i * 256, nullptr, scr, nullptr,
            st, nullptr, c1m + i * 256, c2m + i * 256, nullptr, nullptr, nullptr, 256);
        gemm_bf<false, true, false, false, true, true, false><<<gg, bt, 0, stream>>>(
            nullptr, scr, wtM2 + (size_t)i * 65536, mlp_b2 + i * 256, nullptr, fx, fxh,
            nullptr, st, nullptr, nullptr, nullptr, nullptr, nullptr, 256);
    }
    head_kernel<<<dim3(NP / 4), bt, 0, stream>>>(fx, ln3_g, ln3_b, head_w, head_b, out);
}

// Round 13
// 1249.913 us; speedup vs baseline: 1.3462x; 1.3462x over previous
//
#include <hip/hip_runtime.h>
#include <hip/hip_bf16.h>
#include <math.h>

constexpr int NP  = 32768;  // mesh points
constexpr int HH  = 8;      // heads

typedef short bf16x8 __attribute__((ext_vector_type(8)));
typedef float f32x4  __attribute__((ext_vector_type(4)));

__device__ __forceinline__ float gelu_f(float x) {
    return 0.5f * x * (1.0f + erff(x * 0.70710678118654752f));
}

__device__ __forceinline__ unsigned short f2bf(float x) {
    union { float f; unsigned u; } v; v.f = x;
    unsigned r = v.u + 0x7fffu + ((v.u >> 16) & 1u);
    return (unsigned short)(r >> 16);
}

__device__ __forceinline__ float bf2f(unsigned short h) {
    union { unsigned u; float f; } v; v.u = ((unsigned)h) << 16;
    return v.f;
}

// ---------------------------------------------------------------------------
// Weight prep: src [G][K][256] fp32 -> dst [G][256][K] bf16 (transposed)
// ---------------------------------------------------------------------------
__global__ __launch_bounds__(256) void transpose_bf16_k(
    const float* __restrict__ src, unsigned short* __restrict__ dst, int K)
{
    __shared__ float tile[32][33];
    int g = blockIdx.z;
    int k0 = blockIdx.x * 32, c0 = blockIdx.y * 32;
    int tx = threadIdx.x & 31, ty = threadIdx.x >> 5;
    const float* s = src + (size_t)g * K * 256;
    unsigned short* d = dst + (size_t)g * 256 * K;
    #pragma unroll
    for (int rr = 0; rr < 4; ++rr) {
        int r = ty + rr * 8;
        tile[r][tx] = s[(size_t)(k0 + r) * 256 + c0 + tx];
    }
    __syncthreads();
    #pragma unroll
    for (int rr = 0; rr < 4; ++rr) {
        int r = ty + rr * 8;
        d[(size_t)(c0 + r) * K + k0 + tx] = f2bf(tile[tx][r]);
    }
}

// Same, but scales row k by g[z*256+k] before rounding (LN-fold weights g.W)
__global__ __launch_bounds__(256) void transpose_scale_bf16_k(
    const float* __restrict__ src, const float* __restrict__ g,
    unsigned short* __restrict__ dst, int K)
{
    __shared__ float tile[32][33];
    int z = blockIdx.z;
    int k0 = blockIdx.x * 32, c0 = blockIdx.y * 32;
    int tx = threadIdx.x & 31, ty = threadIdx.x >> 5;
    const float* s = src + (size_t)z * K * 256;
    unsigned short* d = dst + (size_t)z * 256 * K;
    #pragma unroll
    for (int rr = 0; rr < 4; ++rr) {
        int r = ty + rr * 8;
        tile[r][tx] = s[(size_t)(k0 + r) * 256 + c0 + tx];
    }
    __syncthreads();
    float gs = g[z * 256 + k0 + tx];
    #pragma unroll
    for (int rr = 0; rr < 4; ++rr) {
        int r = ty + rr * 8;
        d[(size_t)(c0 + r) * K + k0 + tx] = f2bf(gs * tile[tx][r]);
    }
}

// c2[z][c] = sum_k g[z][k] W[z][k][c] ; c1[z][c] = sum_k b[z][k] W[z][k][c]
__global__ __launch_bounds__(256) void colsum_k(
    const float* __restrict__ W, const float* __restrict__ g,
    const float* __restrict__ b, float* __restrict__ c2, float* __restrict__ c1)
{
    int z = blockIdx.z, c = threadIdx.x;
    const float* Wz = W + (size_t)z * 65536;
    const float* gz = g + z * 256;
    const float* bz = b + z * 256;
    float s2 = 0.f, s1 = 0.f;
    for (int k = 0; k < 256; ++k) {
        float w = Wz[k * 256 + c];
        s2 += gz[k] * w;
        s1 += bz[k] * w;
    }
    c2[z * 256 + c] = s2;
    c1[z * 256 + c] = s1;
}

// wkT[l][d][k] = bf16(wk[l][k][d]); wvT[l][c][k] = bf16(wv[l][k][c])
__global__ __launch_bounds__(256) void prep_wkvT(
    const float* __restrict__ wk, const float* __restrict__ wv,
    unsigned short* __restrict__ wkT, unsigned short* __restrict__ wvT)
{
    int l = blockIdx.x, tid = threadIdx.x;
    for (int idx = tid; idx < 4096; idx += 256) {
        int d = idx >> 5, k = idx & 31;
        wkT[l * 4096 + idx] = f2bf(wk[l * 4096 + k * 128 + d]);
    }
    for (int idx = tid; idx < 1024; idx += 256) {
        int c = idx >> 5, k = idx & 31;
        wvT[l * 1024 + idx] = f2bf(wv[l * 1024 + k * 32 + c]);
    }
}

// ---------------------------------------------------------------------------
// MFMA GEMM (R11-proven BK=64). A sources: GENA / AF32 / bf16.
// LNFOLD epilogue. Writes fp32 (outF) and/or bf16 (outH); PERM writes both.
// ---------------------------------------------------------------------------
template<bool GENA, bool AF32, bool LNFOLD, bool DOGELU, bool RESID, bool STATS, bool PERM>
__global__ __launch_bounds__(256) void gemm_bf(
    const unsigned short* __restrict__ Ah, const float* __restrict__ Af,
    const unsigned short* __restrict__ Wt,
    const float* __restrict__ bias, const float* __restrict__ bias2,
    float* __restrict__ outF, unsigned short* __restrict__ outH,
    const float* __restrict__ stats_in, float* __restrict__ stats_out,
    const float* __restrict__ c1v, const float* __restrict__ c2vec,
    const float* __restrict__ genx, const float* __restrict__ genw1,
    const float* __restrict__ genb1, int K)
{
    __shared__ __align__(16) unsigned short As[128 * 64];
    __shared__ __align__(16) unsigned short Bs[128 * 64];
    __shared__ float rmean[LNFOLD ? 128 : 1];
    __shared__ float rrstd[LNFOLD ? 128 : 1];
    __shared__ float w1s[GENA ? 1536 : 1];
    __shared__ float b1s[GENA ? 512 : 1];
    __shared__ float x3s[GENA ? 512 : 1];

    const int tid = threadIdx.x;
    const int rBase = blockIdx.x * 128, cBase = blockIdx.y * 128;

    if constexpr (GENA) {
        for (int i2 = tid; i2 < 1536; i2 += 256) w1s[i2] = genw1[i2];
        for (int i2 = tid; i2 < 512; i2 += 256) b1s[i2] = genb1[i2];
        if (tid < 128) {
            x3s[tid * 4 + 0] = genx[(size_t)(rBase + tid) * 3 + 0];
            x3s[tid * 4 + 1] = genx[(size_t)(rBase + tid) * 3 + 1];
            x3s[tid * 4 + 2] = genx[(size_t)(rBase + tid) * 3 + 2];
        }
        __syncthreads();
    }
    if constexpr (LNFOLD) {
        if (tid < 128) {
            const float* sp = stats_in + (size_t)(rBase + tid) * 8;
            float4 s0 = *(const float4*)sp;
            float4 s1 = *(const float4*)(sp + 4);
            float mean = (s0.x + s0.z + s1.x + s1.z) * (1.f / 256.f);
            float ex2  = (s0.y + s0.w + s1.y + s1.w) * (1.f / 256.f);
            rmean[tid] = mean;
            rrstd[tid] = rsqrtf(fmaxf(ex2 - mean * mean, 0.f) + 1e-5f);
        }
        __syncthreads();
    }

    f32x4 acc[4][4];
    #pragma unroll
    for (int i = 0; i < 4; ++i)
        #pragma unroll
        for (int j = 0; j < 4; ++j)
            acc[i][j] = (f32x4){0.f, 0.f, 0.f, 0.f};

    const int lane = tid & 63, wid = tid >> 6;
    const int wr = wid >> 1, wc = wid & 1;
    const int lrow = lane & 15, quad = lane >> 4;
    const int srow = tid >> 3;   // 0..31
    const int sch  = tid & 7;    // k-chunk of 8

    for (int kc = 0; kc < K; kc += 64) {
        if constexpr (GENA) {
            #pragma unroll
            for (int it = 0; it < 4; ++it) {
                int row = srow + it * 32;
                float x0 = x3s[row * 4 + 0], x1 = x3s[row * 4 + 1], x2 = x3s[row * 4 + 2];
                unsigned short pk[8];
                #pragma unroll
                for (int j = 0; j < 8; ++j) {
                    int k = kc + sch * 8 + j;
                    float t = x0 * w1s[k] + x1 * w1s[512 + k] + x2 * w1s[1024 + k] + b1s[k];
                    pk[j] = f2bf(gelu_f(t));
                }
                *(uint4*)&As[row * 64 + ((sch ^ (row & 7)) << 3)] = *(uint4*)pk;
            }
        } else if constexpr (AF32) {
            #pragma unroll
            for (int it = 0; it < 4; ++it) {
                int row = srow + it * 32;
                const float* ap = Af + (size_t)(rBase + row) * K + kc + sch * 8;
                float4 a0 = *(const float4*)ap;
                float4 a1 = *(const float4*)(ap + 4);
                unsigned short pk[8];
                pk[0] = f2bf(a0.x); pk[1] = f2bf(a0.y); pk[2] = f2bf(a0.z); pk[3] = f2bf(a0.w);
                pk[4] = f2bf(a1.x); pk[5] = f2bf(a1.y); pk[6] = f2bf(a1.z); pk[7] = f2bf(a1.w);
                *(uint4*)&As[row * 64 + ((sch ^ (row & 7)) << 3)] = *(uint4*)pk;
            }
        } else {
            #pragma unroll
            for (int it = 0; it < 4; ++it) {
                int row = srow + it * 32;
                uint4 av = *(const uint4*)(Ah + (size_t)(rBase + row) * K + kc + sch * 8);
                *(uint4*)&As[row * 64 + ((sch ^ (row & 7)) << 3)] = av;
            }
        }
        #pragma unroll
        for (int it = 0; it < 4; ++it) {
            int n = srow + it * 32;
            uint4 wv_ = *(const uint4*)(Wt + (size_t)(cBase + n) * K + kc + sch * 8);
            *(uint4*)&Bs[n * 64 + ((sch ^ (n & 7)) << 3)] = wv_;
        }
        __syncthreads();
        #pragma unroll
        for (int ks = 0; ks < 2; ++ks) {
            bf16x8 af[4], bfr[4];
            #pragma unroll
            for (int t = 0; t < 4; ++t) {
                int row = wr * 64 + t * 16 + lrow;
                af[t] = *(bf16x8*)&As[row * 64 + (((ks * 4 + quad) ^ (row & 7)) << 3)];
                int n = wc * 64 + t * 16 + lrow;
                bfr[t] = *(bf16x8*)&Bs[n * 64 + (((ks * 4 + quad) ^ (n & 7)) << 3)];
            }
            #pragma unroll
            for (int ti = 0; ti < 4; ++ti)
                #pragma unroll
                for (int tj = 0; tj < 4; ++tj)
                    acc[ti][tj] = __builtin_amdgcn_mfma_f32_16x16x32_bf16(
                        af[ti], bfr[tj], acc[ti][tj], 0, 0, 0);
        }
        __syncthreads();
    }

    float c1b[4], c2r[4];
    #pragma unroll
    for (int tj = 0; tj < 4; ++tj) {
        int gcol = cBase + wc * 64 + tj * 16 + lrow;
        float b = bias[gcol];
        if (bias2) b += bias2[gcol];
        if constexpr (LNFOLD) {
            c1b[tj] = c1v[gcol] + b;
            c2r[tj] = c2vec[gcol];
        } else {
            c1b[tj] = b;
            c2r[tj] = 0.f;
        }
    }
    #pragma unroll
    for (int ti = 0; ti < 4; ++ti) {
        #pragma unroll
        for (int r = 0; r < 4; ++r) {
            int rib = wr * 64 + ti * 16 + quad * 4 + r;
            int grow = rBase + rib;
            float mean = 0.f, rstd = 1.f;
            if constexpr (LNFOLD) { mean = rmean[rib]; rstd = rrstd[rib]; }
            float vv[4];
            #pragma unroll
            for (int tj = 0; tj < 4; ++tj) {
                float t = acc[ti][tj][r];
                float v;
                if constexpr (LNFOLD) v = rstd * (t - mean * c2r[tj]) + c1b[tj];
                else                  v = t + c1b[tj];
                if constexpr (DOGELU) v = gelu_f(v);
                vv[tj] = v;
            }
            if constexpr (RESID) {
                #pragma unroll
                for (int tj = 0; tj < 4; ++tj) {
                    int gcol = cBase + wc * 64 + tj * 16 + lrow;
                    vv[tj] += outF[(size_t)grow * 256 + gcol];
                }
            }
            if constexpr (STATS) {
                float rs = vv[0] + vv[1] + vv[2] + vv[3];
                float rq = vv[0]*vv[0] + vv[1]*vv[1] + vv[2]*vv[2] + vv[3]*vv[3];
                #pragma unroll
                for (int m = 1; m < 16; m <<= 1) {
                    rs += __shfl_xor(rs, m);
                    rq += __shfl_xor(rq, m);
                }
                if (lrow == 0) {
                    stats_out[(size_t)grow * 8 + (blockIdx.y * 2 + wc) * 2 + 0] = rs;
                    stats_out[(size_t)grow * 8 + (blockIdx.y * 2 + wc) * 2 + 1] = rq;
                }
            }
            #pragma unroll
            for (int tj = 0; tj < 4; ++tj) {
                int gcol = cBase + wc * 64 + tj * 16 + lrow;
                if constexpr (PERM) {
                    size_t pidx = (size_t)(gcol >> 5) * NP * 32 + (size_t)grow * 32 + (gcol & 31);
                    outF[pidx] = vv[tj];
                    if (outH) outH[pidx] = f2bf(vv[tj]);
                } else {
                    if (outF) outF[(size_t)grow * 256 + gcol] = vv[tj];
                    if (outH) outH[(size_t)grow * 256 + gcol] = f2bf(vv[tj]);
                }
            }
        }
    }
}

// ---------------------------------------------------------------------------
// kv6 (R13): flash-style MFMA kv. Per (head, 512-row block), 8 subtiles of
// 64 rows: logits & v via mfma(K=32), exp on C-frags (x invtk, clamped),
// e/v rounded to bf16 into LDS [d][row]/[c][row] (C->A/B layout transit),
// kv += e^T v via mfma (fp32 acc). sumexp sums the ROUNDED e (consistent
// with the MFMA numerator). Deterministic; partials format = kv5's.
// ---------------------------------------------------------------------------
__global__ __launch_bounds__(256) void kv6_kernel(
    const unsigned short* __restrict__ xm2h, const unsigned short* __restrict__ wkT,
    const unsigned short* __restrict__ wvT, const float* __restrict__ tk_arr,
    float* __restrict__ partials, int layer)
{
    __shared__ __align__(16) unsigned short xs[64 * 32];
    __shared__ __align__(16) unsigned short wks[128 * 32];
    __shared__ __align__(16) unsigned short wvs[32 * 32];
    __shared__ __align__(16) unsigned short els[128 * 72];  // [d][row], stride 72 (144B, 16B-aligned)
    __shared__ __align__(16) unsigned short vls[32 * 72];   // [c][row]
    __shared__ float sums[4 * 128];

    const int tid = threadIdx.x;
    const int h = blockIdx.y;
    const int rowBase = blockIdx.x * 512;
    const int w = tid >> 6, lane = tid & 63;
    const int lrow = lane & 15, quad = lane >> 4;

    float tk = fminf(fmaxf(tk_arr[layer * 8 + h], 0.1f), 2.0f);
    float invtk = 1.0f / tk;

    // stage wk^T [128 d][32 k] and wv^T [32 c][32 k] (chunk-swizzled)
    #pragma unroll
    for (int it = 0; it < 2; ++it) {
        int cid = tid + it * 256;
        int d = cid >> 2, kc = cid & 3;
        uint4 v = *(const uint4*)(wkT + d * 32 + kc * 8);
        *(uint4*)&wks[d * 32 + ((kc ^ (d & 3)) << 3)] = v;
    }
    if (tid < 128) {
        int c = tid >> 2, kc = tid & 3;
        uint4 v = *(const uint4*)(wvT + c * 32 + kc * 8);
        *(uint4*)&wvs[c * 32 + ((kc ^ (c & 3)) << 3)] = v;
    }

    f32x4 acc2[2][2];
    #pragma unroll
    for (int di = 0; di < 2; ++di)
        #pragma unroll
        for (int ci = 0; ci < 2; ++ci)
            acc2[di][ci] = (f32x4){0.f, 0.f, 0.f, 0.f};
    float seacc[8];
    #pragma unroll
    for (int dt = 0; dt < 8; ++dt) seacc[dt] = 0.f;

    const unsigned short* src = xm2h + (size_t)h * NP * 32 + (size_t)rowBase * 32;

    for (int sub = 0; sub < 8; ++sub) {
        __syncthreads();   // xs/els/vls safe to overwrite (prev mfma done)
        {
            int row = tid >> 2, kc = tid & 3;
            uint4 v = *(const uint4*)(src + (size_t)(sub * 64 + row) * 32 + kc * 8);
            *(uint4*)&xs[row * 32 + ((kc ^ (row & 3)) << 3)] = v;
        }
        __syncthreads();
        // this wave's x A-frag: rows w*16..w*16+15
        int arow = w * 16 + lrow;
        bf16x8 ax = *(bf16x8*)&xs[arow * 32 + ((quad ^ (arow & 3)) << 3)];
        // v = X @ WvT  (2 c-tiles)
        #pragma unroll
        for (int ct = 0; ct < 2; ++ct) {
            int c = ct * 16 + lrow;
            bf16x8 bw = *(bf16x8*)&wvs[c * 32 + ((quad ^ (c & 3)) << 3)];
            f32x4 cc = (f32x4){0.f, 0.f, 0.f, 0.f};
            cc = __builtin_amdgcn_mfma_f32_16x16x32_bf16(ax, bw, cc, 0, 0, 0);
            unsigned short pk[4];
            pk[0] = f2bf(cc[0]); pk[1] = f2bf(cc[1]);
            pk[2] = f2bf(cc[2]); pk[3] = f2bf(cc[3]);
            *(uint2*)&vls[(ct * 16 + lrow) * 72 + w * 16 + quad * 4] = *(uint2*)pk;
        }
        // logits -> e (8 d-tiles)
        #pragma unroll
        for (int dt = 0; dt < 8; ++dt) {
            int d = dt * 16 + lrow;
            bf16x8 bw = *(bf16x8*)&wks[d * 32 + ((quad ^ (d & 3)) << 3)];
            f32x4 cc = (f32x4){0.f, 0.f, 0.f, 0.f};
            cc = __builtin_amdgcn_mfma_f32_16x16x32_bf16(ax, bw, cc, 0, 0, 0);
            unsigned short pk[4];
            float se = 0.f;
            #pragma unroll
            for (int r = 0; r < 4; ++r) {
                float l = fminf(fmaxf(cc[r] * invtk, -30.f), 30.f);
                unsigned short eb = f2bf(__expf(l));
                pk[r] = eb;
                se += bf2f(eb);
            }
            seacc[dt] += se;
            *(uint2*)&els[d * 72 + w * 16 + quad * 4] = *(uint2*)pk;
        }
        __syncthreads();
        // kv += e^T @ v : wave w -> d-tiles 2w,2w+1 x c-tiles 0,1, K=64
        #pragma unroll
        for (int di = 0; di < 2; ++di) {
            int dm = (2 * w + di) * 16 + lrow;
            #pragma unroll
            for (int ks = 0; ks < 2; ++ks) {
                bf16x8 ae = *(bf16x8*)&els[dm * 72 + ks * 32 + quad * 8];
                #pragma unroll
                for (int ci = 0; ci < 2; ++ci) {
                    int cn = ci * 16 + lrow;
                    bf16x8 bv = *(bf16x8*)&vls[cn * 72 + ks * 32 + quad * 8];
                    acc2[di][ci] = __builtin_amdgcn_mfma_f32_16x16x32_bf16(
                        ae, bv, acc2[di][ci], 0, 0, 0);
                }
            }
        }
    }

    // epilogue: kv partial [128 d][32 c] + sumexp partial [128]
    float* outp = partials + ((size_t)h * 64 + blockIdx.x) * 4224;
    #pragma unroll
    for (int di = 0; di < 2; ++di)
        #pragma unroll
        for (int ci = 0; ci < 2; ++ci)
            #pragma unroll
            for (int r = 0; r < 4; ++r) {
                int d = (2 * w + di) * 16 + quad * 4 + r;
                int c = ci * 16 + lrow;
                outp[d * 32 + c] = acc2[di][ci][r];
            }
    #pragma unroll
    for (int dt = 0; dt < 8; ++dt) {
        float s = seacc[dt];
        s += __shfl_xor(s, 16);
        s += __shfl_xor(s, 32);
        if (quad == 0) sums[w * 128 + dt * 16 + lrow] = s;
    }
    __syncthreads();
    if (tid < 128)
        outp[4096 + tid] = sums[tid] + sums[128 + tid] + sums[256 + tid] + sums[384 + tid];
}

__global__ __launch_bounds__(256) void kv_reduce_kernel(
    const float* __restrict__ partials, float* __restrict__ kvU,
    float* __restrict__ sumexp)
{
    int gid = blockIdx.x * 256 + threadIdx.x;
    if (gid >= 8 * 4224) return;
    int h = gid / 4224, idx = gid % 4224;
    const float* base = partials + (size_t)h * 64 * 4224 + idx;
    float s = 0.f;
    #pragma unroll 8
    for (int c = 0; c < 64; ++c) s += base[(size_t)c * 4224];
    if (idx < 4096) kvU[(size_t)h * 4096 + idx] = s;
    else sumexp[h * 128 + (idx - 4096)] = s;
}

// ---------------------------------------------------------------------------
// qkv3 (unchanged R9-proven fp32 version).
// ---------------------------------------------------------------------------
__global__ __launch_bounds__(256) void qkv3_kernel(
    const float* __restrict__ xm2, const float* __restrict__ wq,
    const float* __restrict__ tq_arr,
    const float* __restrict__ kvU, const float* __restrict__ sumexp,
    float* __restrict__ outD, int layer)
{
    __shared__ __align__(16) float xsw[4096];
    __shared__ __align__(16) float wqs[4096];
    __shared__ __align__(16) float kvs[4096];
    __shared__ float ises[128];

    const int tid = threadIdx.x;
    const int h = blockIdx.y;
    const int rowBase = blockIdx.x * 128;
    const int rt = tid >> 4;
    const int dt = tid & 15;

    float tq = fminf(fmaxf(tq_arr[layer * 8 + h], 0.1f), 2.0f);
    float invtq = 1.0f / tq;

    if (tid < 128) ises[tid] = 1.0f / sumexp[h * 128 + tid];
    #pragma unroll
    for (int it = 0; it < 4; ++it) {
        int i4 = tid + it * 256;
        int k = i4 >> 5, c4 = i4 & 31;
        float4 v = *(const float4*)(wq + (size_t)k * 128 + c4 * 4);
        int c4s = c4 ^ ((c4 >> 1) & 7);
        *(float4*)&wqs[k * 128 + c4s * 4] = v;
    }
    {
        const float* kvsrc = kvU + (size_t)h * 4096;
        #pragma unroll
        for (int it = 0; it < 4; ++it) {
            int i4 = tid + it * 256;
            int d = i4 >> 3, c4 = i4 & 7;
            float4 v = *(const float4*)(kvsrc + (size_t)d * 32 + c4 * 4);
            int c4s = c4 ^ ((d >> 3) & 7);
            *(float4*)&kvs[d * 32 + c4s * 4] = v;
        }
    }
    {
        const float* src = xm2 + (size_t)h * NP * 32 + (size_t)rowBase * 32;
        #pragma unroll
        for (int it = 0; it < 4; ++it) {
            int s = tid + it * 256;
            int r = s >> 3, j4 = s & 7;
            float4 v = *(const float4*)(src + (size_t)r * 32 + j4 * 4);
            *(float4*)&xsw[r * 32 + ((j4 ^ ((r >> 3) & 7)) << 2)] = v;
        }
    }
    __syncthreads();

    const int swr = rt & 7;
    const int swd = dt & 7;

    float l[8][8];
    #pragma unroll
    for (int i = 0; i < 8; ++i)
        #pragma unroll
        for (int jd = 0; jd < 8; ++jd) l[i][jd] = 0.f;

    const int cA = (dt * 2)     ^ swd;
    const int cB = (dt * 2 + 1) ^ swd;
    #pragma unroll
    for (int j4 = 0; j4 < 8; ++j4) {
        float4 xv[8];
        #pragma unroll
        for (int i = 0; i < 8; ++i)
            xv[i] = *(const float4*)&xsw[(rt * 8 + i) * 32 + ((j4 ^ swr) << 2)];
        #pragma unroll
        for (int kk = 0; kk < 4; ++kk) {
            int k = j4 * 4 + kk;
            float4 wa = *(const float4*)&wqs[k * 128 + cA * 4];
            float4 wb = *(const float4*)&wqs[k * 128 + cB * 4];
            #pragma unroll
            for (int i = 0; i < 8; ++i) {
                float xx = (kk == 0) ? xv[i].x : (kk == 1) ? xv[i].y
                         : (kk == 2) ? xv[i].z : xv[i].w;
                l[i][0] += xx * wa.x; l[i][1] += xx * wa.y;
                l[i][2] += xx * wa.z; l[i][3] += xx * wa.w;
                l[i][4] += xx * wb.x; l[i][5] += xx * wb.y;
                l[i][6] += xx * wb.z; l[i][7] += xx * wb.w;
            }
        }
    }

    float isr[8];
    #pragma unroll
    for (int jd = 0; jd < 8; ++jd) isr[jd] = ises[dt * 8 + jd];
    #pragma unroll
    for (int i = 0; i < 8; ++i) {
        float m = l[i][0];
        #pragma unroll
        for (int jd = 1; jd < 8; ++jd) m = fmaxf(m, l[i][jd]);
        m = fmaxf(m, __shfl_xor(m, 1));
        m = fmaxf(m, __shfl_xor(m, 2));
        m = fmaxf(m, __shfl_xor(m, 4));
        m = fmaxf(m, __shfl_xor(m, 8));
        float s = 0.f;
        #pragma unroll
        for (int jd = 0; jd < 8; ++jd) {
            float e = __expf((l[i][jd] - m) * invtq);
            l[i][jd] = e;
            s += e;
        }
        s += __shfl_xor(s, 1);
        s += __shfl_xor(s, 2);
        s += __shfl_xor(s, 4);
        s += __shfl_xor(s, 8);
        float inv = 1.0f / s;
        #pragma unroll
        for (int jd = 0; jd < 8; ++jd) l[i][jd] *= inv * isr[jd];
    }

    const int b0 = dt & 1, b1 = (dt >> 1) & 1, b2 = (dt >> 2) & 1, b3 = (dt >> 3) & 1;
    #pragma unroll
    for (int chunk = 0; chunk < 4; ++chunk) {
        float o[8][8];
        #pragma unroll
        for (int i = 0; i < 8; ++i)
            #pragma unroll
            for (int c = 0; c < 8; ++c) o[i][c] = 0.f;
        const int kA = (chunk * 2)     ^ swd;
        const int kB = (chunk * 2 + 1) ^ swd;
        #pragma unroll
        for (int jd = 0; jd < 8; ++jd) {
            int d = dt * 8 + jd;
            float4 ka = *(const float4*)&kvs[d * 32 + kA * 4];
            float4 kb = *(const float4*)&kvs[d * 32 + kB * 4];
            #pragma unroll
            for (int i = 0; i < 8; ++i) {
                float p = l[i][jd];
                o[i][0] += p * ka.x; o[i][1] += p * ka.y;
                o[i][2] += p * ka.z; o[i][3] += p * ka.w;
                o[i][4] += p * kb.x; o[i][5] += p * kb.y;
                o[i][6] += p * kb.z; o[i][7] += p * kb.w;
            }
        }
        float t1[4][8];
        #pragma unroll
        for (int i = 0; i < 4; ++i)
            #pragma unroll
            for (int c = 0; c < 8; ++c) {
                float keep = b0 ? o[i + 4][c] : o[i][c];
                float send = b0 ? o[i][c] : o[i + 4][c];
                t1[i][c] = keep + __shfl_xor(send, 1);
            }
        float t2[2][8];
        #pragma unroll
        for (int i = 0; i < 2; ++i)
            #pragma unroll
            for (int c = 0; c < 8; ++c) {
                float keep = b1 ? t1[i + 2][c] : t1[i][c];
                float send = b1 ? t1[i][c] : t1[i + 2][c];
                t2[i][c] = keep + __shfl_xor(send, 2);
            }
        float t3[2][4];
        #pragma unroll
        for (int i = 0; i < 2; ++i)
            #pragma unroll
            for (int c = 0; c < 4; ++c) {
                float keep = b2 ? t2[i][c + 4] : t2[i][c];
                float send = b2 ? t2[i][c] : t2[i][c + 4];
                t3[i][c] = keep + __shfl_xor(send, 4);
            }
        float t4[4];
        #pragma unroll
        for (int c = 0; c < 4; ++c) {
            float keep = b3 ? t3[1][c] : t3[0][c];
            float send = b3 ? t3[0][c] : t3[1][c];
            t4[c] = keep + __shfl_xor(send, 8);
        }
        int row = rt * 8 + b0 * 4 + b1 * 2 + b3;
        float4 ov; ov.x = t4[0]; ov.y = t4[1]; ov.z = t4[2]; ov.w = t4[3];
        *(float4*)(outD + (size_t)(rowBase + row) * 256 + h * 32 + chunk * 8 + b2 * 4) = ov;
    }
}

// ---------------------------------------------------------------------------
// head: out[n] = LN(fx[n]; ln3) . head_w + head_b
// ---------------------------------------------------------------------------
__global__ __launch_bounds__(256) void head_kernel(
    const float* __restrict__ fx, const float* __restrict__ g, const float* __restrict__ b,
    const float* __restrict__ hw, const float* __restrict__ hb, float* __restrict__ out)
{
    int lane = threadIdx.x & 63;
    int row = blockIdx.x * 4 + (threadIdx.x >> 6);
    float4 v = *(const float4*)(fx + (size_t)row * 256 + lane * 4);
    float s1 = v.x + v.y + v.z + v.w;
    float s2 = v.x * v.x + v.y * v.y + v.z * v.z + v.w * v.w;
    #pragma unroll
    for (int m = 1; m < 64; m <<= 1) { s1 += __shfl_xor(s1, m); s2 += __shfl_xor(s2, m); }
    float mean = s1 * 0.00390625f;
    float rstd = rsqrtf(fmaxf(s2 * 0.00390625f - mean * mean, 0.f) + 1e-5f);
    float4 gg = *(const float4*)(g + lane * 4);
    float4 bb = *(const float4*)(b + lane * 4);
    float4 w4 = *(const float4*)(hw + lane * 4);
    float d = ((v.x - mean) * rstd * gg.x + bb.x) * w4.x
            + ((v.y - mean) * rstd * gg.y + bb.y) * w4.y
            + ((v.z - mean) * rstd * gg.z + bb.z) * w4.z
            + ((v.w - mean) * rstd * gg.w + bb.w) * w4.w;
    #pragma unroll
    for (int m = 1; m < 64; m <<= 1) d += __shfl_xor(d, m);
    if (lane == 0) out[row] = d + hb[0];
}

extern "C" void kernel_launch(void* const* d_in, const int* in_sizes, int n_in,
                              void* d_out, int out_size, void* d_ws, size_t ws_size,
                              hipStream_t stream)
{
    const float* x      = (const float*)d_in[0];
    const float* pre_w1 = (const float*)d_in[1];
    const float* pre_b1 = (const float*)d_in[2];
    const float* pre_w2 = (const float*)d_in[3];
    const float* pre_b2 = (const float*)d_in[4];
    const float* ph     = (const float*)d_in[5];
    const float* ln1_g  = (const float*)d_in[6];
    const float* ln1_b  = (const float*)d_in[7];
    const float* inp_w  = (const float*)d_in[8];
    const float* inp_b  = (const float*)d_in[9];
    const float* temp_q = (const float*)d_in[10];
    const float* temp_k = (const float*)d_in[11];
    const float* wq     = (const float*)d_in[12];
    const float* wk     = (const float*)d_in[13];
    const float* wv     = (const float*)d_in[14];
    const float* out_w1 = (const float*)d_in[15];
    const float* out_b1 = (const float*)d_in[16];
    const float* out_w2 = (const float*)d_in[17];
    const float* out_b2 = (const float*)d_in[18];
    const float* ln2_g  = (const float*)d_in[19];
    const float* ln2_b  = (const float*)d_in[20];
    const float* mlp_w1 = (const float*)d_in[21];
    const float* mlp_b1 = (const float*)d_in[22];
    const float* mlp_w2 = (const float*)d_in[23];
    const float* mlp_b2 = (const float*)d_in[24];
    const float* ln3_g  = (const float*)d_in[25];
    const float* ln3_b  = (const float*)d_in[26];
    const float* head_w = (const float*)d_in[27];
    const float* head_b = (const float*)d_in[28];
    float* out = (float*)d_out;

    // ws: fx f32 | C f32 | fxh bf16 | ChH bf16 (alias xm2h) | scr f32 |
    //     stats | kvU | se | c-vecs | wtPre | wtL | wkT | wvT
    float* fx = (float*)d_ws;
    float* C  = fx + (size_t)NP * 256;
    unsigned short* fxh = (unsigned short*)(C + (size_t)NP * 256);
    unsigned short* ChH = fxh + (size_t)NP * 256;
    unsigned short* xm2h = ChH;                      // alias: lifetimes disjoint
    float* scr = (float*)(ChH + (size_t)NP * 256);
    float* st = scr + (size_t)NP * 256;
    float* kv = st + (size_t)NP * 8;
    float* se = kv + 8 * 4096;
    float* c1i = se + 8 * 128;
    float* c2i = c1i + 1280;
    float* c1m = c2i + 1280;
    float* c2m = c1m + 1280;
    unsigned short* wtPre = (unsigned short*)(c2m + 1280);
    unsigned short* wtL   = wtPre + 256 * 512;
    unsigned short* wkT   = wtL + 25 * 65536;
    unsigned short* wvT   = wkT + 5 * 4096;

    unsigned short* wtIn = wtL;
    unsigned short* wtO1 = wtL +  5 * 65536;
    unsigned short* wtO2 = wtL + 10 * 65536;
    unsigned short* wtM1 = wtL + 15 * 65536;
    unsigned short* wtM2 = wtL + 20 * 65536;

    dim3 bt(256);

    transpose_bf16_k<<<dim3(16, 8, 1), bt, 0, stream>>>(pre_w2, wtPre, 512);
    transpose_scale_bf16_k<<<dim3(8, 8, 5), bt, 0, stream>>>(inp_w,  ln1_g, wtIn, 256);
    transpose_bf16_k<<<dim3(8, 8, 5), bt, 0, stream>>>(out_w1, wtO1, 256);
    transpose_bf16_k<<<dim3(8, 8, 5), bt, 0, stream>>>(out_w2, wtO2, 256);
    transpose_scale_bf16_k<<<dim3(8, 8, 5), bt, 0, stream>>>(mlp_w1, ln2_g, wtM1, 256);
    transpose_bf16_k<<<dim3(8, 8, 5), bt, 0, stream>>>(mlp_w2, wtM2, 256);
    colsum_k<<<dim3(1, 1, 5), bt, 0, stream>>>(inp_w,  ln1_g, ln1_b, c2i, c1i);
    colsum_k<<<dim3(1, 1, 5), bt, 0, stream>>>(mlp_w1, ln2_g, ln2_b, c2m, c1m);
    prep_wkvT<<<dim3(5), bt, 0, stream>>>(wk, wv, wkT, wvT);

    dim3 gg(256, 2);

    gemm_bf<true, false, false, false, false, true, false><<<gg, bt, 0, stream>>>(
        nullptr, nullptr, wtPre, pre_b2, ph, fx, fxh, nullptr, st,
        nullptr, nullptr, x, pre_w1, pre_b1, 512);

    for (int i = 0; i < 5; ++i) {
        // xm2 = perm(LN(fx) @ inp_w + b): fp32 C + bf16 xm2h
        gemm_bf<false, false, true, false, false, false, true><<<gg, bt, 0, stream>>>(
            fxh, nullptr, wtIn + (size_t)i * 65536, inp_b + i * 256, nullptr, C, xm2h,
            st, nullptr, c1i + i * 256, c2i + i * 256, nullptr, nullptr, nullptr, 256);
        // kv via MFMA (partials in scr) + reduce
        kv6_kernel<<<dim3(64, 8), bt, 0, stream>>>(
            xm2h, wkT + (size_t)i * 4096, wvT + (size_t)i * 1024, temp_k, scr, i);
        kv_reduce_kernel<<<dim3(132), bt, 0, stream>>>(scr, kv, se);
        // qkv -> scr (fp32 Dt)
        qkv3_kernel<<<dim3(256, 8), bt, 0, stream>>>(
            C, wq + (size_t)i * 4096, temp_q, kv, se, scr, i);
        // ChH = bf16(GELU(Dt @ out_w1 + b))  [fp32 A staging; overwrites xm2h — kv6 done]
        gemm_bf<false, true, false, true, false, false, false><<<gg, bt, 0, stream>>>(
            nullptr, scr, wtO1 + (size_t)i * 65536, out_b1 + i * 256, nullptr,
            nullptr, ChH, nullptr, nullptr, nullptr, nullptr, nullptr, nullptr, nullptr, 256);
        // fx += Ch @ out_w2 + b (+stats, +fxh)
        gemm_bf<false, false, false, false, true, true, false><<<gg, bt, 0, stream>>>(
            ChH, nullptr, wtO2 + (size_t)i * 65536, out_b2 + i * 256, nullptr, fx, fxh,
            nullptr, st, nullptr, nullptr, nullptr, nullptr, nullptr, 256);
        // scr = GELU(LN(fx) @ mlp_w1 + b)  [LN folded]
        gemm_bf<false, false, true, true, false, false, false><<<gg, bt, 0, stream>>>(
            fxh, nullptr, wtM1 + (size_t)i * 65536, mlp_b1 + i * 256, nullptr, scr, nullptr,
            st, nullptr, c1m + i * 256, c2m + i * 256, nullptr, nullptr, nullptr, 256);
        // fx += Dt @ mlp_w2 + b (+stats, +fxh)
        gemm_bf<false, true, false, false, true, true, false><<<gg, bt, 0, stream>>>(
            nullptr, scr, wtM2 + (size_t)i * 65536, mlp_b2 + i * 256, nullptr, fx, fxh,
            nullptr, st, nullptr, nullptr, nullptr, nullptr, nullptr, 256);
    }
    head_kernel<<<dim3(NP / 4), bt, 0, stream>>>(fx, ln3_g, ln3_b, head_w, head_b, out);
}

// Round 14
// 969.885 us; speedup vs baseline: 1.7349x; 1.2887x over previous
//
#include <hip/hip_runtime.h>
#include <hip/hip_bf16.h>
#include <math.h>

constexpr int NP  = 32768;  // mesh points
constexpr int HH  = 8;      // heads

typedef short bf16x8 __attribute__((ext_vector_type(8)));
typedef float f32x4  __attribute__((ext_vector_type(4)));

__device__ __forceinline__ float gelu_f(float x) {
    return 0.5f * x * (1.0f + erff(x * 0.70710678118654752f));
}

__device__ __forceinline__ unsigned short f2bf(float x) {
    union { float f; unsigned u; } v; v.f = x;
    unsigned r = v.u + 0x7fffu + ((v.u >> 16) & 1u);
    return (unsigned short)(r >> 16);
}

__device__ __forceinline__ float bf2f(unsigned short h) {
    union { unsigned u; float f; } v; v.u = ((unsigned)h) << 16;
    return v.f;
}

// ---------------------------------------------------------------------------
// Weight prep: src [G][K][256] fp32 -> dst [G][256][K] bf16 (transposed)
// ---------------------------------------------------------------------------
__global__ __launch_bounds__(256) void transpose_bf16_k(
    const float* __restrict__ src, unsigned short* __restrict__ dst, int K)
{
    __shared__ float tile[32][33];
    int g = blockIdx.z;
    int k0 = blockIdx.x * 32, c0 = blockIdx.y * 32;
    int tx = threadIdx.x & 31, ty = threadIdx.x >> 5;
    const float* s = src + (size_t)g * K * 256;
    unsigned short* d = dst + (size_t)g * 256 * K;
    #pragma unroll
    for (int rr = 0; rr < 4; ++rr) {
        int r = ty + rr * 8;
        tile[r][tx] = s[(size_t)(k0 + r) * 256 + c0 + tx];
    }
    __syncthreads();
    #pragma unroll
    for (int rr = 0; rr < 4; ++rr) {
        int r = ty + rr * 8;
        d[(size_t)(c0 + r) * K + k0 + tx] = f2bf(tile[tx][r]);
    }
}

// Same, but scales row k by g[z*256+k] before rounding (LN-fold weights g.W)
__global__ __launch_bounds__(256) void transpose_scale_bf16_k(
    const float* __restrict__ src, const float* __restrict__ g,
    unsigned short* __restrict__ dst, int K)
{
    __shared__ float tile[32][33];
    int z = blockIdx.z;
    int k0 = blockIdx.x * 32, c0 = blockIdx.y * 32;
    int tx = threadIdx.x & 31, ty = threadIdx.x >> 5;
    const float* s = src + (size_t)z * K * 256;
    unsigned short* d = dst + (size_t)z * 256 * K;
    #pragma unroll
    for (int rr = 0; rr < 4; ++rr) {
        int r = ty + rr * 8;
        tile[r][tx] = s[(size_t)(k0 + r) * 256 + c0 + tx];
    }
    __syncthreads();
    float gs = g[z * 256 + k0 + tx];
    #pragma unroll
    for (int rr = 0; rr < 4; ++rr) {
        int r = ty + rr * 8;
        d[(size_t)(c0 + r) * K + k0 + tx] = f2bf(gs * tile[tx][r]);
    }
}

// c2[z][c] = sum_k g[z][k] W[z][k][c] ; c1[z][c] = sum_k b[z][k] W[z][k][c]
__global__ __launch_bounds__(256) void colsum_k(
    const float* __restrict__ W, const float* __restrict__ g,
    const float* __restrict__ b, float* __restrict__ c2, float* __restrict__ c1)
{
    int z = blockIdx.z, c = threadIdx.x;
    const float* Wz = W + (size_t)z * 65536;
    const float* gz = g + z * 256;
    const float* bz = b + z * 256;
    float s2 = 0.f, s1 = 0.f;
    for (int k = 0; k < 256; ++k) {
        float w = Wz[k * 256 + c];
        s2 += gz[k] * w;
        s1 += bz[k] * w;
    }
    c2[z * 256 + c] = s2;
    c1[z * 256 + c] = s1;
}

// wkT[l][d][k]=bf16(wk[l][k][d]); wvT[l][c][k]=bf16(wv[l][k][c]);
// wqT[l][d][k]=bf16(wq[l][k][d])
__global__ __launch_bounds__(256) void prep_wkvT(
    const float* __restrict__ wk, const float* __restrict__ wv,
    const float* __restrict__ wq,
    unsigned short* __restrict__ wkT, unsigned short* __restrict__ wvT,
    unsigned short* __restrict__ wqT)
{
    int l = blockIdx.x, tid = threadIdx.x;
    for (int idx = tid; idx < 4096; idx += 256) {
        int d = idx >> 5, k = idx & 31;
        wkT[l * 4096 + idx] = f2bf(wk[l * 4096 + k * 128 + d]);
        wqT[l * 4096 + idx] = f2bf(wq[l * 4096 + k * 128 + d]);
    }
    for (int idx = tid; idx < 1024; idx += 256) {
        int c = idx >> 5, k = idx & 31;
        wvT[l * 1024 + idx] = f2bf(wv[l * 1024 + k * 32 + c]);
    }
}

// ---------------------------------------------------------------------------
// MFMA GEMM (BK=64 proven). A sources: GENA / AF32 / bf16. LNFOLD epilogue.
// ---------------------------------------------------------------------------
template<bool GENA, bool AF32, bool LNFOLD, bool DOGELU, bool RESID, bool STATS, bool PERM>
__global__ __launch_bounds__(256) void gemm_bf(
    const unsigned short* __restrict__ Ah, const float* __restrict__ Af,
    const unsigned short* __restrict__ Wt,
    const float* __restrict__ bias, const float* __restrict__ bias2,
    float* __restrict__ outF, unsigned short* __restrict__ outH,
    const float* __restrict__ stats_in, float* __restrict__ stats_out,
    const float* __restrict__ c1v, const float* __restrict__ c2vec,
    const float* __restrict__ genx, const float* __restrict__ genw1,
    const float* __restrict__ genb1, int K)
{
    __shared__ __align__(16) unsigned short As[128 * 64];
    __shared__ __align__(16) unsigned short Bs[128 * 64];
    __shared__ float rmean[LNFOLD ? 128 : 1];
    __shared__ float rrstd[LNFOLD ? 128 : 1];
    __shared__ float w1s[GENA ? 1536 : 1];
    __shared__ float b1s[GENA ? 512 : 1];
    __shared__ float x3s[GENA ? 512 : 1];

    const int tid = threadIdx.x;
    const int rBase = blockIdx.x * 128, cBase = blockIdx.y * 128;

    if constexpr (GENA) {
        for (int i2 = tid; i2 < 1536; i2 += 256) w1s[i2] = genw1[i2];
        for (int i2 = tid; i2 < 512; i2 += 256) b1s[i2] = genb1[i2];
        if (tid < 128) {
            x3s[tid * 4 + 0] = genx[(size_t)(rBase + tid) * 3 + 0];
            x3s[tid * 4 + 1] = genx[(size_t)(rBase + tid) * 3 + 1];
            x3s[tid * 4 + 2] = genx[(size_t)(rBase + tid) * 3 + 2];
        }
        __syncthreads();
    }
    if constexpr (LNFOLD) {
        if (tid < 128) {
            const float* sp = stats_in + (size_t)(rBase + tid) * 8;
            float4 s0 = *(const float4*)sp;
            float4 s1 = *(const float4*)(sp + 4);
            float mean = (s0.x + s0.z + s1.x + s1.z) * (1.f / 256.f);
            float ex2  = (s0.y + s0.w + s1.y + s1.w) * (1.f / 256.f);
            rmean[tid] = mean;
            rrstd[tid] = rsqrtf(fmaxf(ex2 - mean * mean, 0.f) + 1e-5f);
        }
        __syncthreads();
    }

    f32x4 acc[4][4];
    #pragma unroll
    for (int i = 0; i < 4; ++i)
        #pragma unroll
        for (int j = 0; j < 4; ++j)
            acc[i][j] = (f32x4){0.f, 0.f, 0.f, 0.f};

    const int lane = tid & 63, wid = tid >> 6;
    const int wr = wid >> 1, wc = wid & 1;
    const int lrow = lane & 15, quad = lane >> 4;
    const int srow = tid >> 3;   // 0..31
    const int sch  = tid & 7;    // k-chunk of 8

    for (int kc = 0; kc < K; kc += 64) {
        if constexpr (GENA) {
            #pragma unroll
            for (int it = 0; it < 4; ++it) {
                int row = srow + it * 32;
                float x0 = x3s[row * 4 + 0], x1 = x3s[row * 4 + 1], x2 = x3s[row * 4 + 2];
                unsigned short pk[8];
                #pragma unroll
                for (int j = 0; j < 8; ++j) {
                    int k = kc + sch * 8 + j;
                    float t = x0 * w1s[k] + x1 * w1s[512 + k] + x2 * w1s[1024 + k] + b1s[k];
                    pk[j] = f2bf(gelu_f(t));
                }
                *(uint4*)&As[row * 64 + ((sch ^ (row & 7)) << 3)] = *(uint4*)pk;
            }
        } else if constexpr (AF32) {
            #pragma unroll
            for (int it = 0; it < 4; ++it) {
                int row = srow + it * 32;
                const float* ap = Af + (size_t)(rBase + row) * K + kc + sch * 8;
                float4 a0 = *(const float4*)ap;
                float4 a1 = *(const float4*)(ap + 4);
                unsigned short pk[8];
                pk[0] = f2bf(a0.x); pk[1] = f2bf(a0.y); pk[2] = f2bf(a0.z); pk[3] = f2bf(a0.w);
                pk[4] = f2bf(a1.x); pk[5] = f2bf(a1.y); pk[6] = f2bf(a1.z); pk[7] = f2bf(a1.w);
                *(uint4*)&As[row * 64 + ((sch ^ (row & 7)) << 3)] = *(uint4*)pk;
            }
        } else {
            #pragma unroll
            for (int it = 0; it < 4; ++it) {
                int row = srow + it * 32;
                uint4 av = *(const uint4*)(Ah + (size_t)(rBase + row) * K + kc + sch * 8);
                *(uint4*)&As[row * 64 + ((sch ^ (row & 7)) << 3)] = av;
            }
        }
        #pragma unroll
        for (int it = 0; it < 4; ++it) {
            int n = srow + it * 32;
            uint4 wv_ = *(const uint4*)(Wt + (size_t)(cBase + n) * K + kc + sch * 8);
            *(uint4*)&Bs[n * 64 + ((sch ^ (n & 7)) << 3)] = wv_;
        }
        __syncthreads();
        #pragma unroll
        for (int ks = 0; ks < 2; ++ks) {
            bf16x8 af[4], bfr[4];
            #pragma unroll
            for (int t = 0; t < 4; ++t) {
                int row = wr * 64 + t * 16 + lrow;
                af[t] = *(bf16x8*)&As[row * 64 + (((ks * 4 + quad) ^ (row & 7)) << 3)];
                int n = wc * 64 + t * 16 + lrow;
                bfr[t] = *(bf16x8*)&Bs[n * 64 + (((ks * 4 + quad) ^ (n & 7)) << 3)];
            }
            #pragma unroll
            for (int ti = 0; ti < 4; ++ti)
                #pragma unroll
                for (int tj = 0; tj < 4; ++tj)
                    acc[ti][tj] = __builtin_amdgcn_mfma_f32_16x16x32_bf16(
                        af[ti], bfr[tj], acc[ti][tj], 0, 0, 0);
        }
        __syncthreads();
    }

    float c1b[4], c2r[4];
    #pragma unroll
    for (int tj = 0; tj < 4; ++tj) {
        int gcol = cBase + wc * 64 + tj * 16 + lrow;
        float b = bias[gcol];
        if (bias2) b += bias2[gcol];
        if constexpr (LNFOLD) {
            c1b[tj] = c1v[gcol] + b;
            c2r[tj] = c2vec[gcol];
        } else {
            c1b[tj] = b;
            c2r[tj] = 0.f;
        }
    }
    #pragma unroll
    for (int ti = 0; ti < 4; ++ti) {
        #pragma unroll
        for (int r = 0; r < 4; ++r) {
            int rib = wr * 64 + ti * 16 + quad * 4 + r;
            int grow = rBase + rib;
            float mean = 0.f, rstd = 1.f;
            if constexpr (LNFOLD) { mean = rmean[rib]; rstd = rrstd[rib]; }
            float vv[4];
            #pragma unroll
            for (int tj = 0; tj < 4; ++tj) {
                float t = acc[ti][tj][r];
                float v;
                if constexpr (LNFOLD) v = rstd * (t - mean * c2r[tj]) + c1b[tj];
                else                  v = t + c1b[tj];
                if constexpr (DOGELU) v = gelu_f(v);
                vv[tj] = v;
            }
            if constexpr (RESID) {
                #pragma unroll
                for (int tj = 0; tj < 4; ++tj) {
                    int gcol = cBase + wc * 64 + tj * 16 + lrow;
                    vv[tj] += outF[(size_t)grow * 256 + gcol];
                }
            }
            if constexpr (STATS) {
                float rs = vv[0] + vv[1] + vv[2] + vv[3];
                float rq = vv[0]*vv[0] + vv[1]*vv[1] + vv[2]*vv[2] + vv[3]*vv[3];
                #pragma unroll
                for (int m = 1; m < 16; m <<= 1) {
                    rs += __shfl_xor(rs, m);
                    rq += __shfl_xor(rq, m);
                }
                if (lrow == 0) {
                    stats_out[(size_t)grow * 8 + (blockIdx.y * 2 + wc) * 2 + 0] = rs;
                    stats_out[(size_t)grow * 8 + (blockIdx.y * 2 + wc) * 2 + 1] = rq;
                }
            }
            #pragma unroll
            for (int tj = 0; tj < 4; ++tj) {
                int gcol = cBase + wc * 64 + tj * 16 + lrow;
                if constexpr (PERM) {
                    size_t pidx = (size_t)(gcol >> 5) * NP * 32 + (size_t)grow * 32 + (gcol & 31);
                    if (outF) outF[pidx] = vv[tj];
                    if (outH) outH[pidx] = f2bf(vv[tj]);
                } else {
                    if (outF) outF[(size_t)grow * 256 + gcol] = vv[tj];
                    if (outH) outH[(size_t)grow * 256 + gcol] = f2bf(vv[tj]);
                }
            }
        }
    }
}

// ---------------------------------------------------------------------------
// kv6 (unchanged, working): flash-style MFMA kv.
// ---------------------------------------------------------------------------
__global__ __launch_bounds__(256) void kv6_kernel(
    const unsigned short* __restrict__ xm2h, const unsigned short* __restrict__ wkT,
    const unsigned short* __restrict__ wvT, const float* __restrict__ tk_arr,
    float* __restrict__ partials, int layer)
{
    __shared__ __align__(16) unsigned short xs[64 * 32];
    __shared__ __align__(16) unsigned short wks[128 * 32];
    __shared__ __align__(16) unsigned short wvs[32 * 32];
    __shared__ __align__(16) unsigned short els[128 * 72];
    __shared__ __align__(16) unsigned short vls[32 * 72];
    __shared__ float sums[4 * 128];

    const int tid = threadIdx.x;
    const int h = blockIdx.y;
    const int rowBase = blockIdx.x * 512;
    const int w = tid >> 6, lane = tid & 63;
    const int lrow = lane & 15, quad = lane >> 4;

    float tk = fminf(fmaxf(tk_arr[layer * 8 + h], 0.1f), 2.0f);
    float invtk = 1.0f / tk;

    #pragma unroll
    for (int it = 0; it < 2; ++it) {
        int cid = tid + it * 256;
        int d = cid >> 2, kc = cid & 3;
        uint4 v = *(const uint4*)(wkT + d * 32 + kc * 8);
        *(uint4*)&wks[d * 32 + ((kc ^ (d & 3)) << 3)] = v;
    }
    if (tid < 128) {
        int c = tid >> 2, kc = tid & 3;
        uint4 v = *(const uint4*)(wvT + c * 32 + kc * 8);
        *(uint4*)&wvs[c * 32 + ((kc ^ (c & 3)) << 3)] = v;
    }

    f32x4 acc2[2][2];
    #pragma unroll
    for (int di = 0; di < 2; ++di)
        #pragma unroll
        for (int ci = 0; ci < 2; ++ci)
            acc2[di][ci] = (f32x4){0.f, 0.f, 0.f, 0.f};
    float seacc[8];
    #pragma unroll
    for (int dt = 0; dt < 8; ++dt) seacc[dt] = 0.f;

    const unsigned short* src = xm2h + (size_t)h * NP * 32 + (size_t)rowBase * 32;

    for (int sub = 0; sub < 8; ++sub) {
        __syncthreads();
        {
            int row = tid >> 2, kc = tid & 3;
            uint4 v = *(const uint4*)(src + (size_t)(sub * 64 + row) * 32 + kc * 8);
            *(uint4*)&xs[row * 32 + ((kc ^ (row & 3)) << 3)] = v;
        }
        __syncthreads();
        int arow = w * 16 + lrow;
        bf16x8 ax = *(bf16x8*)&xs[arow * 32 + ((quad ^ (arow & 3)) << 3)];
        #pragma unroll
        for (int ct = 0; ct < 2; ++ct) {
            int c = ct * 16 + lrow;
            bf16x8 bw = *(bf16x8*)&wvs[c * 32 + ((quad ^ (c & 3)) << 3)];
            f32x4 cc = (f32x4){0.f, 0.f, 0.f, 0.f};
            cc = __builtin_amdgcn_mfma_f32_16x16x32_bf16(ax, bw, cc, 0, 0, 0);
            unsigned short pk[4];
            pk[0] = f2bf(cc[0]); pk[1] = f2bf(cc[1]);
            pk[2] = f2bf(cc[2]); pk[3] = f2bf(cc[3]);
            *(uint2*)&vls[(ct * 16 + lrow) * 72 + w * 16 + quad * 4] = *(uint2*)pk;
        }
        #pragma unroll
        for (int dt = 0; dt < 8; ++dt) {
            int d = dt * 16 + lrow;
            bf16x8 bw = *(bf16x8*)&wks[d * 32 + ((quad ^ (d & 3)) << 3)];
            f32x4 cc = (f32x4){0.f, 0.f, 0.f, 0.f};
            cc = __builtin_amdgcn_mfma_f32_16x16x32_bf16(ax, bw, cc, 0, 0, 0);
            unsigned short pk[4];
            float se = 0.f;
            #pragma unroll
            for (int r = 0; r < 4; ++r) {
                float l = fminf(fmaxf(cc[r] * invtk, -30.f), 30.f);
                unsigned short eb = f2bf(__expf(l));
                pk[r] = eb;
                se += bf2f(eb);
            }
            seacc[dt] += se;
            *(uint2*)&els[d * 72 + w * 16 + quad * 4] = *(uint2*)pk;
        }
        __syncthreads();
        #pragma unroll
        for (int di = 0; di < 2; ++di) {
            int dm = (2 * w + di) * 16 + lrow;
            #pragma unroll
            for (int ks = 0; ks < 2; ++ks) {
                bf16x8 ae = *(bf16x8*)&els[dm * 72 + ks * 32 + quad * 8];
                #pragma unroll
                for (int ci = 0; ci < 2; ++ci) {
                    int cn = ci * 16 + lrow;
                    bf16x8 bv = *(bf16x8*)&vls[cn * 72 + ks * 32 + quad * 8];
                    acc2[di][ci] = __builtin_amdgcn_mfma_f32_16x16x32_bf16(
                        ae, bv, acc2[di][ci], 0, 0, 0);
                }
            }
        }
    }

    float* outp = partials + ((size_t)h * 64 + blockIdx.x) * 4224;
    #pragma unroll
    for (int di = 0; di < 2; ++di)
        #pragma unroll
        for (int ci = 0; ci < 2; ++ci)
            #pragma unroll
            for (int r = 0; r < 4; ++r) {
                int d = (2 * w + di) * 16 + quad * 4 + r;
                int c = ci * 16 + lrow;
                outp[d * 32 + c] = acc2[di][ci][r];
            }
    #pragma unroll
    for (int dt = 0; dt < 8; ++dt) {
        float s = seacc[dt];
        s += __shfl_xor(s, 16);
        s += __shfl_xor(s, 32);
        if (quad == 0) sums[w * 128 + dt * 16 + lrow] = s;
    }
    __syncthreads();
    if (tid < 128)
        outp[4096 + tid] = sums[tid] + sums[128 + tid] + sums[256 + tid] + sums[384 + tid];
}

// kv_reduce (R14): emits bf16 kvT[h][c][d] (for qkv6's B operand) + sumexp.
__global__ __launch_bounds__(256) void kv_reduce_kernel(
    const float* __restrict__ partials, unsigned short* __restrict__ kvT,
    float* __restrict__ sumexp)
{
    int gid = blockIdx.x * 256 + threadIdx.x;
    if (gid >= 8 * 4224) return;
    int h = gid / 4224, idx = gid % 4224;
    const float* base = partials + (size_t)h * 64 * 4224 + idx;
    float s = 0.f;
    #pragma unroll 8
    for (int c = 0; c < 64; ++c) s += base[(size_t)c * 4224];
    if (idx < 4096) {
        int d = idx >> 5, c = idx & 31;
        kvT[(size_t)h * 4096 + c * 128 + d] = f2bf(s);
    } else {
        sumexp[h * 128 + (idx - 4096)] = s;
    }
}

// ---------------------------------------------------------------------------
// qkv6 (R14): MFMA qkv. Per (64-row tile, head): logits X@WqT via 8 MFMAs,
// softmax on C-frags (per-r reduce over 8 dt regs + shfl_xor over lrow),
// p = e/s * ises[d] rounded bf16 into els[row][d] (stride 136); PV E@KVT
// via 8 MFMAs (kvT bf16 [c][d]). No barrier between phases (wave-local els).
// ---------------------------------------------------------------------------
__global__ __launch_bounds__(256) void qkv6_kernel(
    const unsigned short* __restrict__ xm2h, const unsigned short* __restrict__ wqT,
    const float* __restrict__ tq_arr, const unsigned short* __restrict__ kvT,
    const float* __restrict__ sumexp, float* __restrict__ outD, int layer)
{
    __shared__ __align__(16) unsigned short xs[64 * 32];
    __shared__ __align__(16) unsigned short wqs[128 * 32];
    __shared__ __align__(16) unsigned short kvb[32 * 136];
    __shared__ __align__(16) unsigned short els[64 * 136];
    __shared__ float ises[128];

    const int tid = threadIdx.x;
    const int h = blockIdx.y;
    const int rowBase = blockIdx.x * 64;
    const int w = tid >> 6, lane = tid & 63;
    const int lrow = lane & 15, quad = lane >> 4;

    float tq = fminf(fmaxf(tq_arr[layer * 8 + h], 0.1f), 2.0f);
    float invtq = 1.0f / tq;

    if (tid < 128) ises[tid] = 1.0f / sumexp[h * 128 + tid];
    #pragma unroll
    for (int it = 0; it < 2; ++it) {
        int cid = tid + it * 256;
        int d = cid >> 2, kc = cid & 3;
        uint4 v = *(const uint4*)(wqT + d * 32 + kc * 8);
        *(uint4*)&wqs[d * 32 + ((kc ^ (d & 3)) << 3)] = v;
    }
    #pragma unroll
    for (int it = 0; it < 2; ++it) {
        int cid = tid + it * 256;          // 0..511
        int c = cid >> 4, k8 = cid & 15;
        uint4 v = *(const uint4*)(kvT + (size_t)h * 4096 + c * 128 + k8 * 8);
        *(uint4*)&kvb[c * 136 + k8 * 8] = v;
    }
    {
        int row = tid >> 2, kc = tid & 3;
        uint4 v = *(const uint4*)(xm2h + (size_t)h * NP * 32 +
                                  (size_t)(rowBase + row) * 32 + kc * 8);
        *(uint4*)&xs[row * 32 + ((kc ^ (row & 3)) << 3)] = v;
    }
    __syncthreads();

    // ---- logits: 8 d-tiles for this wave's 16 rows ----
    int arow = w * 16 + lrow;
    bf16x8 ax = *(bf16x8*)&xs[arow * 32 + ((quad ^ (arow & 3)) << 3)];
    f32x4 lg[8];
    #pragma unroll
    for (int dt = 0; dt < 8; ++dt) {
        int d = dt * 16 + lrow;
        bf16x8 bw = *(bf16x8*)&wqs[d * 32 + ((quad ^ (d & 3)) << 3)];
        f32x4 cc = (f32x4){0.f, 0.f, 0.f, 0.f};
        lg[dt] = __builtin_amdgcn_mfma_f32_16x16x32_bf16(ax, bw, cc, 0, 0, 0);
    }
    float isv[8];
    #pragma unroll
    for (int dt = 0; dt < 8; ++dt) isv[dt] = ises[dt * 16 + lrow];

    // ---- softmax per output row (quad*4+r), d spread over dt regs x lrow ----
    #pragma unroll
    for (int r = 0; r < 4; ++r) {
        float m = lg[0][r];
        #pragma unroll
        for (int dt = 1; dt < 8; ++dt) m = fmaxf(m, lg[dt][r]);
        m = fmaxf(m, __shfl_xor(m, 1));
        m = fmaxf(m, __shfl_xor(m, 2));
        m = fmaxf(m, __shfl_xor(m, 4));
        m = fmaxf(m, __shfl_xor(m, 8));
        float e[8], s = 0.f;
        #pragma unroll
        for (int dt = 0; dt < 8; ++dt) {
            e[dt] = __expf((lg[dt][r] - m) * invtq);
            s += e[dt];
        }
        s += __shfl_xor(s, 1);
        s += __shfl_xor(s, 2);
        s += __shfl_xor(s, 4);
        s += __shfl_xor(s, 8);
        float inv = 1.0f / s;
        int erow = w * 16 + quad * 4 + r;
        #pragma unroll
        for (int dt = 0; dt < 8; ++dt)
            els[erow * 136 + dt * 16 + lrow] = f2bf(e[dt] * inv * isv[dt]);
    }

    // ---- PV: rows w*16..+15 (wave-local els; compiler orders LDS ops) ----
    #pragma unroll
    for (int ct = 0; ct < 2; ++ct) {
        f32x4 oc = (f32x4){0.f, 0.f, 0.f, 0.f};
        #pragma unroll
        for (int ks = 0; ks < 4; ++ks) {
            bf16x8 ae = *(bf16x8*)&els[(w * 16 + lrow) * 136 + ks * 32 + quad * 8];
            bf16x8 bv = *(bf16x8*)&kvb[(ct * 16 + lrow) * 136 + ks * 32 + quad * 8];
            oc = __builtin_amdgcn_mfma_f32_16x16x32_bf16(ae, bv, oc, 0, 0, 0);
        }
        #pragma unroll
        for (int r = 0; r < 4; ++r)
            outD[(size_t)(rowBase + w * 16 + quad * 4 + r) * 256 +
                 h * 32 + ct * 16 + lrow] = oc[r];
    }
}

// ---------------------------------------------------------------------------
// head: out[n] = LN(fx[n]; ln3) . head_w + head_b
// ---------------------------------------------------------------------------
__global__ __launch_bounds__(256) void head_kernel(
    const float* __restrict__ fx, const float* __restrict__ g, const float* __restrict__ b,
    const float* __restrict__ hw, const float* __restrict__ hb, float* __restrict__ out)
{
    int lane = threadIdx.x & 63;
    int row = blockIdx.x * 4 + (threadIdx.x >> 6);
    float4 v = *(const float4*)(fx + (size_t)row * 256 + lane * 4);
    float s1 = v.x + v.y + v.z + v.w;
    float s2 = v.x * v.x + v.y * v.y + v.z * v.z + v.w * v.w;
    #pragma unroll
    for (int m = 1; m < 64; m <<= 1) { s1 += __shfl_xor(s1, m); s2 += __shfl_xor(s2, m); }
    float mean = s1 * 0.00390625f;
    float rstd = rsqrtf(fmaxf(s2 * 0.00390625f - mean * mean, 0.f) + 1e-5f);
    float4 gg = *(const float4*)(g + lane * 4);
    float4 bb = *(const float4*)(b + lane * 4);
    float4 w4 = *(const float4*)(hw + lane * 4);
    float d = ((v.x - mean) * rstd * gg.x + bb.x) * w4.x
            + ((v.y - mean) * rstd * gg.y + bb.y) * w4.y
            + ((v.z - mean) * rstd * gg.z + bb.z) * w4.z
            + ((v.w - mean) * rstd * gg.w + bb.w) * w4.w;
    #pragma unroll
    for (int m = 1; m < 64; m <<= 1) d += __shfl_xor(d, m);
    if (lane == 0) out[row] = d + hb[0];
}

extern "C" void kernel_launch(void* const* d_in, const int* in_sizes, int n_in,
                              void* d_out, int out_size, void* d_ws, size_t ws_size,
                              hipStream_t stream)
{
    const float* x      = (const float*)d_in[0];
    const float* pre_w1 = (const float*)d_in[1];
    const float* pre_b1 = (const float*)d_in[2];
    const float* pre_w2 = (const float*)d_in[3];
    const float* pre_b2 = (const float*)d_in[4];
    const float* ph     = (const float*)d_in[5];
    const float* ln1_g  = (const float*)d_in[6];
    const float* ln1_b  = (const float*)d_in[7];
    const float* inp_w  = (const float*)d_in[8];
    const float* inp_b  = (const float*)d_in[9];
    const float* temp_q = (const float*)d_in[10];
    const float* temp_k = (const float*)d_in[11];
    const float* wq     = (const float*)d_in[12];
    const float* wk     = (const float*)d_in[13];
    const float* wv     = (const float*)d_in[14];
    const float* out_w1 = (const float*)d_in[15];
    const float* out_b1 = (const float*)d_in[16];
    const float* out_w2 = (const float*)d_in[17];
    const float* out_b2 = (const float*)d_in[18];
    const float* ln2_g  = (const float*)d_in[19];
    const float* ln2_b  = (const float*)d_in[20];
    const float* mlp_w1 = (const float*)d_in[21];
    const float* mlp_b1 = (const float*)d_in[22];
    const float* mlp_w2 = (const float*)d_in[23];
    const float* mlp_b2 = (const float*)d_in[24];
    const float* ln3_g  = (const float*)d_in[25];
    const float* ln3_b  = (const float*)d_in[26];
    const float* head_w = (const float*)d_in[27];
    const float* head_b = (const float*)d_in[28];
    float* out = (float*)d_out;

    // ws: fx f32 | fxh bf16 | xm2h bf16 (alias ChH) | ChH | scr f32 |
    //     stats | kvT bf16 | se | c-vecs | wtPre | wtL | wkT | wvT | wqT
    float* fx = (float*)d_ws;
    unsigned short* fxh = (unsigned short*)(fx + (size_t)NP * 256);
    unsigned short* ChH = fxh + (size_t)NP * 256;
    unsigned short* xm2h = ChH;                      // alias: lifetimes disjoint
    float* scr = (float*)(ChH + (size_t)NP * 256);
    float* st = scr + (size_t)NP * 256;
    unsigned short* kvT = (unsigned short*)(st + (size_t)NP * 8);
    float* se = (float*)(kvT + 8 * 4096);
    float* c1i = se + 8 * 128;
    float* c2i = c1i + 1280;
    float* c1m = c2i + 1280;
    float* c2m = c1m + 1280;
    unsigned short* wtPre = (unsigned short*)(c2m + 1280);
    unsigned short* wtL   = wtPre + 256 * 512;
    unsigned short* wkT   = wtL + 25 * 65536;
    unsigned short* wvT   = wkT + 5 * 4096;
    unsigned short* wqT   = wvT + 5 * 1024;

    unsigned short* wtIn = wtL;
    unsigned short* wtO1 = wtL +  5 * 65536;
    unsigned short* wtO2 = wtL + 10 * 65536;
    unsigned short* wtM1 = wtL + 15 * 65536;
    unsigned short* wtM2 = wtL + 20 * 65536;

    dim3 bt(256);

    transpose_bf16_k<<<dim3(16, 8, 1), bt, 0, stream>>>(pre_w2, wtPre, 512);
    transpose_scale_bf16_k<<<dim3(8, 8, 5), bt, 0, stream>>>(inp_w,  ln1_g, wtIn, 256);
    transpose_bf16_k<<<dim3(8, 8, 5), bt, 0, stream>>>(out_w1, wtO1, 256);
    transpose_bf16_k<<<dim3(8, 8, 5), bt, 0, stream>>>(out_w2, wtO2, 256);
    transpose_scale_bf16_k<<<dim3(8, 8, 5), bt, 0, stream>>>(mlp_w1, ln2_g, wtM1, 256);
    transpose_bf16_k<<<dim3(8, 8, 5), bt, 0, stream>>>(mlp_w2, wtM2, 256);
    colsum_k<<<dim3(1, 1, 5), bt, 0, stream>>>(inp_w,  ln1_g, ln1_b, c2i, c1i);
    colsum_k<<<dim3(1, 1, 5), bt, 0, stream>>>(mlp_w1, ln2_g, ln2_b, c2m, c1m);
    prep_wkvT<<<dim3(5), bt, 0, stream>>>(wk, wv, wq, wkT, wvT, wqT);

    dim3 gg(256, 2);

    gemm_bf<true, false, false, false, false, true, false><<<gg, bt, 0, stream>>>(
        nullptr, nullptr, wtPre, pre_b2, ph, fx, fxh, nullptr, st,
        nullptr, nullptr, x, pre_w1, pre_b1, 512);

    for (int i = 0; i < 5; ++i) {
        // xm2h = bf16 perm(LN(fx) @ inp_w + b)  [no fp32 copy needed]
        gemm_bf<false, false, true, false, false, false, true><<<gg, bt, 0, stream>>>(
            fxh, nullptr, wtIn + (size_t)i * 65536, inp_b + i * 256, nullptr, nullptr, xm2h,
            st, nullptr, c1i + i * 256, c2i + i * 256, nullptr, nullptr, nullptr, 256);
        // kv via MFMA (partials in scr) + reduce -> kvT bf16 + se
        kv6_kernel<<<dim3(64, 8), bt, 0, stream>>>(
            xm2h, wkT + (size_t)i * 4096, wvT + (size_t)i * 1024, temp_k, scr, i);
        kv_reduce_kernel<<<dim3(132), bt, 0, stream>>>(scr, kvT, se);
        // qkv via MFMA -> scr (fp32 Dt)
        qkv6_kernel<<<dim3(512, 8), bt, 0, stream>>>(
            xm2h, wqT + (size_t)i * 4096, temp_q, kvT, se, scr, i);
        // ChH = bf16(GELU(Dt @ out_w1 + b))  [fp32 A; overwrites xm2h — done]
        gemm_bf<false, true, false, true, false, false, false><<<gg, bt, 0, stream>>>(
            nullptr, scr, wtO1 + (size_t)i * 65536, out_b1 + i * 256, nullptr,
            nullptr, ChH, nullptr, nullptr, nullptr, nullptr, nullptr, nullptr, nullptr, 256);
        // fx += Ch @ out_w2 + b (+stats, +fxh)
        gemm_bf<false, false, false, false, true, true, false><<<gg, bt, 0, stream>>>(
            ChH, nullptr, wtO2 + (size_t)i * 65536, out_b2 + i * 256, nullptr, fx, fxh,
            nullptr, st, nullptr, nullptr, nullptr, nullptr, nullptr, 256);
        // scr = GELU(LN(fx) @ mlp_w1 + b)  [LN folded]
        gemm_bf<false, false, true, true, false, false, false><<<gg, bt, 0, stream>>>(
            fxh, nullptr, wtM1 + (size_t)i * 65536, mlp_b1 + i * 256, nullptr, scr, nullptr,
            st, nullptr, c1m + i * 256, c2m + i * 256, nullptr, nullptr, nullptr, 256);
        // fx += Dt @ mlp_w2 + b (+stats, +fxh)
        gemm_bf<false, true, false, false, true, true, false><<<gg, bt, 0, stream>>>(
            nullptr, scr, wtM2 + (size_t)i * 65536, mlp_b2 + i * 256, nullptr, fx, fxh,
            nullptr, st, nullptr, nullptr, nullptr, nullptr, nullptr, 256);
    }
    head_kernel<<<dim3(NP / 4), bt, 0, stream>>>(fx, ln3_g, ln3_b, head_w, head_b, out);
}